// Round 1
// baseline (774.085 us; speedup 1.0000x reference)
//
#include <hip/hip_runtime.h>
#include <hip/hip_bf16.h>

#define LEAKY(v) ((v) > 0.f ? (v) : 0.2f * (v))

struct ConstBuf {
    float ws[3][4];      // per-branch, per-head: dot(W[h,:], a_s[h,:])
    float wd[3][4];      // dot(W[h,:], a_d[h,:])
    float M[3][3][4];    // [branch][attr_k][head]: dot(We[k, h*16+..], a_e[h,:])
    float G[12][128];    // folded branch-W through Wf
    float bias2[128];    // bf + concat-bias through Wf
};

struct BranchW { const float *W, *as_, *ad_, *ae, *We, *b; };
struct PreArgs { BranchW br[3]; const float *Wf, *bf; ConstBuf* cb; };

// ---------------- precompute folded weight constants (1 block) ----------------
__global__ void k_precompute(PreArgs A) {
    int t = threadIdx.x; // 256 threads
    if (t < 24) {
        int b = t / 8, r = t % 8, h = r & 3; bool isd = r >= 4;
        const float* a = isd ? A.br[b].ad_ : A.br[b].as_;
        float s = 0.f;
        for (int c = 0; c < 16; ++c) s += A.br[b].W[h * 16 + c] * a[h * 16 + c];
        if (isd) A.cb->wd[b][h] = s; else A.cb->ws[b][h] = s;
    }
    if (t >= 32 && t < 68) {
        int id = t - 32, b = id / 12, k = (id % 12) / 4, h = id & 3;
        float s = 0.f;
        for (int c = 0; c < 16; ++c) s += A.br[b].We[k * 64 + h * 16 + c] * A.br[b].ae[h * 16 + c];
        A.cb->M[b][k][h] = s;
    }
    if (t >= 128) {
        int j = t - 128;
        float s = A.bf[j];
        for (int b = 0; b < 3; ++b)
            for (int i = 0; i < 64; ++i)
                s += A.br[b].b[i] * A.Wf[(b * 64 + i) * 128 + j];
        A.cb->bias2[j] = s;
    }
    for (int id = t; id < 1536; id += 256) {
        int r = id >> 7, j = id & 127, b = r >> 2, h = r & 3;
        float s = 0.f;
        for (int c = 0; c < 16; ++c)
            s += A.br[b].W[h * 16 + c] * A.Wf[(b * 64 + h * 16 + c) * 128 + j];
        A.cb->G[r][j] = s;
    }
}

// ---------------- CSR build ----------------
__global__ void k_count(const int* __restrict__ ei, int E, int* __restrict__ deg) {
    int e = blockIdx.x * blockDim.x + threadIdx.x;
    if (e < E) atomicAdd(&deg[ei[E + e]], 1);
}

__global__ void k_scan(const int* __restrict__ deg, int* __restrict__ off,
                       int* __restrict__ cursor, int n) {
    __shared__ int sd[1024];
    int t = threadIdx.x;
    int total = n + 1;
    int chunk = (total + 1023) / 1024;
    int base = t * chunk;
    int s = 0;
    for (int i = 0; i < chunk; ++i) {
        int idx = base + i;
        if (idx < n) s += deg[idx];
    }
    sd[t] = s;
    __syncthreads();
    for (int ofs = 1; ofs < 1024; ofs <<= 1) {
        int v = (t >= ofs) ? sd[t - ofs] : 0;
        __syncthreads();
        sd[t] += v;
        __syncthreads();
    }
    int run = sd[t] - s; // exclusive prefix
    for (int i = 0; i < chunk; ++i) {
        int idx = base + i;
        if (idx < total) {
            off[idx] = run;
            if (idx < n) { cursor[idx] = run; run += deg[idx]; }
        }
    }
}

__global__ void k_scatter(const int* __restrict__ ei, int E, int* __restrict__ cursor,
                          int* __restrict__ csr_src, int* __restrict__ csr_eid) {
    int e = blockIdx.x * blockDim.x + threadIdx.x;
    if (e < E) {
        int d = ei[E + e];
        int p = atomicAdd(&cursor[d], 1);
        csr_src[p] = ei[e];
        csr_eid[p] = e;
    }
}

// ---------------- branch GATs: per-node gather -> S[N,12] ----------------
__global__ void k_branch(const float* __restrict__ x, const float* __restrict__ attr,
                         const int* __restrict__ mt, const int* __restrict__ mg,
                         const int* __restrict__ mp, const int* __restrict__ off,
                         const int* __restrict__ csr_src, const int* __restrict__ csr_eid,
                         const ConstBuf* __restrict__ cb, float* __restrict__ S, int N) {
    __shared__ float cc[60]; // ws[12], wd[12], M[36]
    if (threadIdx.x < 60) cc[threadIdx.x] = ((const float*)cb)[threadIdx.x];
    __syncthreads();
    int n = blockIdx.x * blockDim.x + threadIdx.x;
    if (n >= N) return;

    float num[12], den[12], asum[9], cnt[3];
    #pragma unroll
    for (int i = 0; i < 12; ++i) { num[i] = 0.f; den[i] = 0.f; }
    #pragma unroll
    for (int i = 0; i < 9; ++i) asum[i] = 0.f;
    cnt[0] = cnt[1] = cnt[2] = 0.f;

    float xn = x[n];
    int beg = off[n], end = off[n + 1];
    for (int p = beg; p < end; ++p) {
        int src = csr_src[p];
        int e = csr_eid[p];
        float xs = x[src];
        float a0 = attr[e * 3 + 0], a1 = attr[e * 3 + 1], a2 = attr[e * 3 + 2];
        int mm[3] = { mt[e], mg[e], mp[e] };
        #pragma unroll
        for (int b = 0; b < 3; ++b) {
            if (mm[b]) {
                cnt[b] += 1.f;
                asum[b * 3 + 0] += a0; asum[b * 3 + 1] += a1; asum[b * 3 + 2] += a2;
                #pragma unroll
                for (int h = 0; h < 4; ++h) {
                    float al = xs * cc[b * 4 + h] + xn * cc[12 + b * 4 + h]
                             + a0 * cc[24 + b * 12 + 0 + h]
                             + a1 * cc[24 + b * 12 + 4 + h]
                             + a2 * cc[24 + b * 12 + 8 + h];
                    al = LEAKY(al);
                    float ex = __expf(al);
                    den[b * 4 + h] += ex;
                    num[b * 4 + h] += ex * xs;
                }
            }
        }
    }
    #pragma unroll
    for (int b = 0; b < 3; ++b) {
        float inv = 1.f / fmaxf(cnt[b], 1.f);
        float l0 = asum[b * 3 + 0] * inv, l1 = asum[b * 3 + 1] * inv, l2 = asum[b * 3 + 2] * inv;
        #pragma unroll
        for (int h = 0; h < 4; ++h) {
            float lp = xn * (cc[b * 4 + h] + cc[12 + b * 4 + h])
                     + l0 * cc[24 + b * 12 + 0 + h]
                     + l1 * cc[24 + b * 12 + 4 + h]
                     + l2 * cc[24 + b * 12 + 8 + h];
            lp = LEAKY(lp);
            float exl = __expf(lp);
            float sden = den[b * 4 + h] + exl;
            S[(size_t)n * 12 + b * 4 + h] = (num[b * 4 + h] + exl * xn) / sden;
        }
    }
}

// ---------------- h = relu(S @ G + bias2) ----------------
__global__ void k_fuse(const float* __restrict__ S, const ConstBuf* __restrict__ cb,
                       float* __restrict__ h, int N) {
    int tid = blockIdx.x * blockDim.x + threadIdx.x;
    int n = tid >> 7, j = tid & 127;
    if (n >= N) return;
    const float* Sn = S + (size_t)n * 12;
    float acc = cb->bias2[j];
    #pragma unroll
    for (int k = 0; k < 12; ++k) acc += Sn[k] * cb->G[k][j];
    h[(size_t)n * 128 + j] = fmaxf(acc, 0.f);
}

// ---------------- [N,128] @ [128,128] ----------------
__global__ void k_mm128(const float* __restrict__ A, const float* __restrict__ W,
                        float* __restrict__ Out, int N) {
    __shared__ float As[8 * 128];
    int j = threadIdx.x; // 128 threads
    int n0 = blockIdx.x * 8;
    #pragma unroll
    for (int i = 0; i < 8; ++i) {
        int n = n0 + i;
        As[i * 128 + j] = (n < N) ? A[(size_t)n * 128 + j] : 0.f;
    }
    __syncthreads();
    float acc[8] = {0.f, 0.f, 0.f, 0.f, 0.f, 0.f, 0.f, 0.f};
    for (int k = 0; k < 128; ++k) {
        float wv = W[k * 128 + j];
        #pragma unroll
        for (int i = 0; i < 8; ++i) acc[i] += As[i * 128 + k] * wv;
    }
    #pragma unroll
    for (int i = 0; i < 8; ++i) {
        int n = n0 + i;
        if (n < N) Out[(size_t)n * 128 + j] = acc[i];
    }
}

// ---------------- attention scores per (node, head) ----------------
__global__ void k_scores(const float* __restrict__ hx, const float* __restrict__ a_s,
                         const float* __restrict__ a_d, float* __restrict__ as_,
                         float* __restrict__ ad_, int N) {
    int tid = blockIdx.x * blockDim.x + threadIdx.x;
    int n = tid >> 2, h = tid & 3;
    if (n >= N) return;
    const float4* row = (const float4*)(hx + (size_t)n * 128 + h * 32);
    const float4* vs = (const float4*)(a_s + h * 32);
    const float4* vd = (const float4*)(a_d + h * 32);
    float ss = 0.f, sd2 = 0.f;
    #pragma unroll
    for (int q = 0; q < 8; ++q) {
        float4 v = row[q], s4 = vs[q], d4 = vd[q];
        ss  += v.x * s4.x + v.y * s4.y + v.z * s4.z + v.w * s4.w;
        sd2 += v.x * d4.x + v.y * d4.y + v.z * d4.z + v.w * d4.w;
    }
    as_[(size_t)n * 4 + h] = ss;
    ad_[(size_t)n * 4 + h] = sd2;
}

// ---------------- GAT aggregation (conv2/conv3): wave per node ----------------
__global__ void k_gatagg(const float* __restrict__ hx, const float* __restrict__ as_,
                         const float* __restrict__ ad_, const float* __restrict__ b,
                         const int* __restrict__ off, const int* __restrict__ csr_src,
                         float* __restrict__ out, int N) {
    int wave = threadIdx.x >> 6, lane = threadIdx.x & 63;
    int n = blockIdx.x * 4 + wave;
    if (n >= N) return;
    int h = lane >> 4;
    float adn = ad_[(size_t)n * 4 + h];
    int beg = off[n], end = off[n + 1];
    float acc0 = 0.f, acc1 = 0.f, accd = 0.f;
    for (int p = beg; p < end; ++p) {
        int src = csr_src[p];
        float al = LEAKY(as_[(size_t)src * 4 + h] + adn);
        float ex = __expf(al);
        float2 v = *(const float2*)(hx + (size_t)src * 128 + lane * 2);
        acc0 += ex * v.x; acc1 += ex * v.y; accd += ex;
    }
    float aln = LEAKY(as_[(size_t)n * 4 + h] + adn);
    float exl = __expf(aln);
    float2 vn = *(const float2*)(hx + (size_t)n * 128 + lane * 2);
    float inv = 1.f / (accd + exl);
    float o0 = (acc0 + exl * vn.x) * inv + b[lane * 2 + 0];
    float o1 = (acc1 + exl * vn.y) * inv + b[lane * 2 + 1];
    float2 r; r.x = fmaxf(o0, 0.f); r.y = fmaxf(o1, 0.f);
    *(float2*)(out + (size_t)n * 128 + lane * 2) = r;
}

// ---------------- classifier + log_softmax: wave per node ----------------
__global__ void k_cls(const float* __restrict__ h3, const float* __restrict__ Wc1,
                      const float* __restrict__ bc1, const float* __restrict__ Wc2,
                      const float* __restrict__ bc2, float* __restrict__ out, int N) {
    __shared__ float hs[4 * 128];
    int tid = threadIdx.x;
    int nb = blockIdx.x * 4;
    for (int i = tid; i < 512; i += 256) {
        int n = nb + (i >> 7);
        hs[i] = (n < N) ? h3[(size_t)n * 128 + (i & 127)] : 0.f;
    }
    __syncthreads();
    int wave = tid >> 6, lane = tid & 63;
    int n = nb + wave;
    if (n >= N) return;
    const float* hr = hs + wave * 128;
    float t = bc1[lane];
    for (int k = 0; k < 128; ++k) t += hr[k] * Wc1[k * 64 + lane];
    t = fmaxf(t, 0.f);
    float p[5];
    #pragma unroll
    for (int c = 0; c < 5; ++c) p[c] = t * Wc2[lane * 5 + c];
    #pragma unroll
    for (int m = 1; m < 64; m <<= 1) {
        #pragma unroll
        for (int c = 0; c < 5; ++c) p[c] += __shfl_xor(p[c], m, 64);
    }
    if (lane == 0) {
        float l[5], mx = -1e30f;
        #pragma unroll
        for (int c = 0; c < 5; ++c) { l[c] = p[c] + bc2[c]; mx = fmaxf(mx, l[c]); }
        float s = 0.f;
        #pragma unroll
        for (int c = 0; c < 5; ++c) s += __expf(l[c] - mx);
        float lse = mx + __logf(s);
        #pragma unroll
        for (int c = 0; c < 5; ++c) out[(size_t)n * 5 + c] = l[c] - lse;
    }
}

extern "C" void kernel_launch(void* const* d_in, const int* in_sizes, int n_in,
                              void* d_out, int out_size, void* d_ws, size_t ws_size,
                              hipStream_t stream) {
    const float* x    = (const float*)d_in[0];
    const int*   ei   = (const int*)d_in[1];
    const float* attr = (const float*)d_in[2];
    const int*   mt   = (const int*)d_in[3];
    const int*   mg   = (const int*)d_in[4];
    const int*   mp   = (const int*)d_in[5];
    const float* Wf   = (const float*)d_in[24];
    const float* bf   = (const float*)d_in[25];
    const float* W2   = (const float*)d_in[26];
    const float* a2s  = (const float*)d_in[27];
    const float* a2d  = (const float*)d_in[28];
    const float* b2   = (const float*)d_in[29];
    const float* W3   = (const float*)d_in[30];
    const float* a3s  = (const float*)d_in[31];
    const float* a3d  = (const float*)d_in[32];
    const float* b3   = (const float*)d_in[33];
    const float* Wc1  = (const float*)d_in[34];
    const float* bc1  = (const float*)d_in[35];
    const float* Wc2  = (const float*)d_in[36];
    const float* bc2  = (const float*)d_in[37];

    int N = in_sizes[0];
    int E = in_sizes[1] / 2;

    // workspace carve (aligned to 256B)
    char* w = (char*)d_ws;
    auto alloc = [&](size_t bytes) {
        char* p = w;
        w += (bytes + 255) & ~(size_t)255;
        return p;
    };
    int* off     = (int*)alloc((size_t)(N + 1) * 4);
    int* cursor  = (int*)alloc((size_t)N * 4);
    int* deg     = (int*)alloc((size_t)N * 4);
    int* csr_src = (int*)alloc((size_t)E * 4);
    int* csr_eid = (int*)alloc((size_t)E * 4);
    ConstBuf* cb = (ConstBuf*)alloc(sizeof(ConstBuf));
    float* S     = (float*)alloc((size_t)N * 12 * 4);
    float* as_   = (float*)alloc((size_t)N * 4 * 4);
    float* ad_   = (float*)alloc((size_t)N * 4 * 4);
    float* bufA  = (float*)alloc((size_t)N * 128 * 4);
    float* bufB  = (float*)alloc((size_t)N * 128 * 4);

    PreArgs pa;
    for (int b = 0; b < 3; ++b) {
        pa.br[b].W   = (const float*)d_in[6 + b * 6 + 0];
        pa.br[b].as_ = (const float*)d_in[6 + b * 6 + 1];
        pa.br[b].ad_ = (const float*)d_in[6 + b * 6 + 2];
        pa.br[b].ae  = (const float*)d_in[6 + b * 6 + 3];
        pa.br[b].We  = (const float*)d_in[6 + b * 6 + 4];
        pa.br[b].b   = (const float*)d_in[6 + b * 6 + 5];
    }
    pa.Wf = Wf; pa.bf = bf; pa.cb = cb;

    hipMemsetAsync(deg, 0, (size_t)N * 4, stream);
    hipLaunchKernelGGL(k_precompute, dim3(1), dim3(256), 0, stream, pa);
    int gE = (E + 255) / 256;
    hipLaunchKernelGGL(k_count, dim3(gE), dim3(256), 0, stream, ei, E, deg);
    hipLaunchKernelGGL(k_scan, dim3(1), dim3(1024), 0, stream, deg, off, cursor, N);
    hipLaunchKernelGGL(k_scatter, dim3(gE), dim3(256), 0, stream, ei, E, cursor, csr_src, csr_eid);
    hipLaunchKernelGGL(k_branch, dim3((N + 255) / 256), dim3(256), 0, stream,
                       x, attr, mt, mg, mp, off, csr_src, csr_eid, cb, S, N);
    hipLaunchKernelGGL(k_fuse, dim3(((size_t)N * 128 + 255) / 256), dim3(256), 0, stream,
                       S, cb, bufA, N);
    // conv2: hx2 = h @ W2 -> bufB; aggregate -> h2 in bufA
    hipLaunchKernelGGL(k_mm128, dim3((N + 7) / 8), dim3(128), 0, stream, bufA, W2, bufB, N);
    hipLaunchKernelGGL(k_scores, dim3(((size_t)N * 4 + 255) / 256), dim3(256), 0, stream,
                       bufB, a2s, a2d, as_, ad_, N);
    hipLaunchKernelGGL(k_gatagg, dim3((N + 3) / 4), dim3(256), 0, stream,
                       bufB, as_, ad_, b2, off, csr_src, bufA, N);
    // conv3: hx3 = h2 @ W3 -> bufB; aggregate -> h3 in bufA
    hipLaunchKernelGGL(k_mm128, dim3((N + 7) / 8), dim3(128), 0, stream, bufA, W3, bufB, N);
    hipLaunchKernelGGL(k_scores, dim3(((size_t)N * 4 + 255) / 256), dim3(256), 0, stream,
                       bufB, a3s, a3d, as_, ad_, N);
    hipLaunchKernelGGL(k_gatagg, dim3((N + 3) / 4), dim3(256), 0, stream,
                       bufB, as_, ad_, b3, off, csr_src, bufA, N);
    // classifier
    hipLaunchKernelGGL(k_cls, dim3((N + 3) / 4), dim3(256), 0, stream,
                       bufA, Wc1, bc1, Wc2, bc2, (float*)d_out, N);
}

// Round 2
// 629.876 us; speedup vs baseline: 1.2289x; 1.2289x over previous
//
#include <hip/hip_runtime.h>
#include <hip/hip_bf16.h>

#define LEAKY(v) ((v) > 0.f ? (v) : 0.2f * (v))

struct ConstBuf {
    float ws[3][4];      // per-branch, per-head: dot(W[h,:], a_s[h,:])
    float wd[3][4];      // dot(W[h,:], a_d[h,:])
    float M[3][3][4];    // [branch][attr_k][head]: dot(We[k, h*16+..], a_e[h,:])
    float G[12][128];    // folded branch-W through Wf
    float bias2[128];    // bf + concat-bias through Wf
};

struct BranchW { const float *W, *as_, *ad_, *ae, *We, *b; };
struct PreArgs { BranchW br[3]; const float *Wf, *bf; ConstBuf* cb; };

// ---------------- precompute folded weight constants (1 block) ----------------
__global__ void k_precompute(PreArgs A) {
    int t = threadIdx.x; // 256 threads
    if (t < 24) {
        int b = t / 8, r = t % 8, h = r & 3; bool isd = r >= 4;
        const float* a = isd ? A.br[b].ad_ : A.br[b].as_;
        float s = 0.f;
        for (int c = 0; c < 16; ++c) s += A.br[b].W[h * 16 + c] * a[h * 16 + c];
        if (isd) A.cb->wd[b][h] = s; else A.cb->ws[b][h] = s;
    }
    if (t >= 32 && t < 68) {
        int id = t - 32, b = id / 12, k = (id % 12) / 4, h = id & 3;
        float s = 0.f;
        for (int c = 0; c < 16; ++c) s += A.br[b].We[k * 64 + h * 16 + c] * A.br[b].ae[h * 16 + c];
        A.cb->M[b][k][h] = s;
    }
    if (t >= 128) {
        int j = t - 128;
        float s = A.bf[j];
        for (int b = 0; b < 3; ++b)
            for (int i = 0; i < 64; ++i)
                s += A.br[b].b[i] * A.Wf[(b * 64 + i) * 128 + j];
        A.cb->bias2[j] = s;
    }
    for (int id = t; id < 1536; id += 256) {
        int r = id >> 7, j = id & 127, b = r >> 2, h = r & 3;
        float s = 0.f;
        for (int c = 0; c < 16; ++c)
            s += A.br[b].W[h * 16 + c] * A.Wf[(b * 64 + h * 16 + c) * 128 + j];
        A.cb->G[r][j] = s;
    }
}

// ---------------- CSR build ----------------
__global__ void k_count(const int* __restrict__ ei, int E, int* __restrict__ deg) {
    int e = blockIdx.x * blockDim.x + threadIdx.x;
    if (e < E) atomicAdd(&deg[ei[E + e]], 1);
}

// hierarchical scan: 2048 elems per 256-thread block
#define SCAN_EPB 2048

__global__ void k_scan1(const int* __restrict__ deg, int* __restrict__ off,
                        int* __restrict__ partials, int total) {
    __shared__ int sd[256];
    int t = threadIdx.x;
    int base = blockIdx.x * SCAN_EPB + t * 8;
    int v[8];
    int s = 0;
    #pragma unroll
    for (int i = 0; i < 8; ++i) {
        int idx = base + i;
        v[i] = (idx < total - 1) ? deg[idx] : 0; // entry n (== total-1) contributes 0
        s += v[i];
    }
    sd[t] = s;
    __syncthreads();
    #pragma unroll
    for (int ofs = 1; ofs < 256; ofs <<= 1) {
        int u = (t >= ofs) ? sd[t - ofs] : 0;
        __syncthreads();
        sd[t] += u;
        __syncthreads();
    }
    if (t == 255) partials[blockIdx.x] = sd[255];
    int run = sd[t] - s; // exclusive prefix within block
    #pragma unroll
    for (int i = 0; i < 8; ++i) {
        int idx = base + i;
        if (idx < total) off[idx] = run;
        run += v[i];
    }
}

__global__ void k_scan2(int* __restrict__ partials, int nb) {
    __shared__ int sd[256];
    int t = threadIdx.x;
    int v = (t < nb) ? partials[t] : 0;
    sd[t] = v;
    __syncthreads();
    #pragma unroll
    for (int ofs = 1; ofs < 256; ofs <<= 1) {
        int u = (t >= ofs) ? sd[t - ofs] : 0;
        __syncthreads();
        sd[t] += u;
        __syncthreads();
    }
    if (t < nb) partials[t] = sd[t] - v; // exclusive
}

__global__ void k_scan3(int* __restrict__ off, const int* __restrict__ partials,
                        int* __restrict__ cursor, int total) {
    int idx = blockIdx.x * blockDim.x + threadIdx.x;
    if (idx < total) {
        int v = off[idx] + partials[idx / SCAN_EPB];
        off[idx] = v;
        if (idx < total - 1) cursor[idx] = v;
    }
}

// scatter edges into CSR order, packing attr + mask bits per edge
__global__ void k_scatter(const int* __restrict__ ei, const float* __restrict__ attr,
                          const int* __restrict__ mt, const int* __restrict__ mg,
                          const int* __restrict__ mp, int E, int* __restrict__ cursor,
                          int* __restrict__ csr_src, float4* __restrict__ rec) {
    int e = blockIdx.x * blockDim.x + threadIdx.x;
    if (e < E) {
        int d = ei[E + e];
        int p = atomicAdd(&cursor[d], 1);
        csr_src[p] = ei[e];
        float4 r;
        r.x = attr[e * 3 + 0];
        r.y = attr[e * 3 + 1];
        r.z = attr[e * 3 + 2];
        int bits = (mt[e] != 0 ? 1 : 0) | (mg[e] != 0 ? 2 : 0) | (mp[e] != 0 ? 4 : 0);
        r.w = __int_as_float(bits);
        rec[p] = r;
    }
}

// ---------------- branch GATs: per-node gather -> S[N,12] ----------------
__global__ void k_branch(const float* __restrict__ x, const int* __restrict__ off,
                         const int* __restrict__ csr_src, const float4* __restrict__ rec,
                         const ConstBuf* __restrict__ cb, float* __restrict__ S, int N) {
    __shared__ float cc[60]; // ws[12], wd[12], M[36]
    if (threadIdx.x < 60) cc[threadIdx.x] = ((const float*)cb)[threadIdx.x];
    __syncthreads();
    int n = blockIdx.x * blockDim.x + threadIdx.x;
    if (n >= N) return;

    float num[12], den[12], asum[9], cnt[3];
    #pragma unroll
    for (int i = 0; i < 12; ++i) { num[i] = 0.f; den[i] = 0.f; }
    #pragma unroll
    for (int i = 0; i < 9; ++i) asum[i] = 0.f;
    cnt[0] = cnt[1] = cnt[2] = 0.f;

    float xn = x[n];
    int beg = off[n], end = off[n + 1];
    for (int p = beg; p < end; ++p) {
        int src = csr_src[p];
        float4 r = rec[p];
        float xs = x[src];
        float a0 = r.x, a1 = r.y, a2 = r.z;
        int bits = __float_as_int(r.w);
        #pragma unroll
        for (int b = 0; b < 3; ++b) {
            if ((bits >> b) & 1) {
                cnt[b] += 1.f;
                asum[b * 3 + 0] += a0; asum[b * 3 + 1] += a1; asum[b * 3 + 2] += a2;
                #pragma unroll
                for (int h = 0; h < 4; ++h) {
                    float al = xs * cc[b * 4 + h] + xn * cc[12 + b * 4 + h]
                             + a0 * cc[24 + b * 12 + 0 + h]
                             + a1 * cc[24 + b * 12 + 4 + h]
                             + a2 * cc[24 + b * 12 + 8 + h];
                    al = LEAKY(al);
                    float ex = __expf(al);
                    den[b * 4 + h] += ex;
                    num[b * 4 + h] += ex * xs;
                }
            }
        }
    }
    #pragma unroll
    for (int b = 0; b < 3; ++b) {
        float inv = 1.f / fmaxf(cnt[b], 1.f);
        float l0 = asum[b * 3 + 0] * inv, l1 = asum[b * 3 + 1] * inv, l2 = asum[b * 3 + 2] * inv;
        #pragma unroll
        for (int h = 0; h < 4; ++h) {
            float lp = xn * (cc[b * 4 + h] + cc[12 + b * 4 + h])
                     + l0 * cc[24 + b * 12 + 0 + h]
                     + l1 * cc[24 + b * 12 + 4 + h]
                     + l2 * cc[24 + b * 12 + 8 + h];
            lp = LEAKY(lp);
            float exl = __expf(lp);
            float sden = den[b * 4 + h] + exl;
            S[(size_t)n * 12 + b * 4 + h] = (num[b * 4 + h] + exl * xn) / sden;
        }
    }
}

// ---------------- h = relu(S @ G + bias2) ----------------
__global__ void k_fuse(const float* __restrict__ S, const ConstBuf* __restrict__ cb,
                       float* __restrict__ h, int N) {
    int tid = blockIdx.x * blockDim.x + threadIdx.x;
    int n = tid >> 7, j = tid & 127;
    if (n >= N) return;
    const float* Sn = S + (size_t)n * 12;
    float acc = cb->bias2[j];
    #pragma unroll
    for (int k = 0; k < 12; ++k) acc += Sn[k] * cb->G[k][j];
    h[(size_t)n * 128 + j] = fmaxf(acc, 0.f);
}

// ---------------- [N,128] @ [128,128] ----------------
__global__ void k_mm128(const float* __restrict__ A, const float* __restrict__ W,
                        float* __restrict__ Out, int N) {
    __shared__ float As[8 * 128];
    int j = threadIdx.x; // 128 threads
    int n0 = blockIdx.x * 8;
    #pragma unroll
    for (int i = 0; i < 8; ++i) {
        int n = n0 + i;
        As[i * 128 + j] = (n < N) ? A[(size_t)n * 128 + j] : 0.f;
    }
    __syncthreads();
    float acc[8] = {0.f, 0.f, 0.f, 0.f, 0.f, 0.f, 0.f, 0.f};
    for (int k = 0; k < 128; ++k) {
        float wv = W[k * 128 + j];
        #pragma unroll
        for (int i = 0; i < 8; ++i) acc[i] += As[i * 128 + k] * wv;
    }
    #pragma unroll
    for (int i = 0; i < 8; ++i) {
        int n = n0 + i;
        if (n < N) Out[(size_t)n * 128 + j] = acc[i];
    }
}

// ---------------- attention scores per (node, head) ----------------
__global__ void k_scores(const float* __restrict__ hx, const float* __restrict__ a_s,
                         const float* __restrict__ a_d, float* __restrict__ as_,
                         float* __restrict__ ad_, int N) {
    int tid = blockIdx.x * blockDim.x + threadIdx.x;
    int n = tid >> 2, h = tid & 3;
    if (n >= N) return;
    const float4* row = (const float4*)(hx + (size_t)n * 128 + h * 32);
    const float4* vs = (const float4*)(a_s + h * 32);
    const float4* vd = (const float4*)(a_d + h * 32);
    float ss = 0.f, sd2 = 0.f;
    #pragma unroll
    for (int q = 0; q < 8; ++q) {
        float4 v = row[q], s4 = vs[q], d4 = vd[q];
        ss  += v.x * s4.x + v.y * s4.y + v.z * s4.z + v.w * s4.w;
        sd2 += v.x * d4.x + v.y * d4.y + v.z * d4.z + v.w * d4.w;
    }
    as_[(size_t)n * 4 + h] = ss;
    ad_[(size_t)n * 4 + h] = sd2;
}

// ---------------- GAT aggregation (conv2/conv3): wave per node ----------------
__global__ void k_gatagg(const float* __restrict__ hx, const float* __restrict__ as_,
                         const float* __restrict__ ad_, const float* __restrict__ b,
                         const int* __restrict__ off, const int* __restrict__ csr_src,
                         float* __restrict__ out, int N) {
    int wave = threadIdx.x >> 6, lane = threadIdx.x & 63;
    int n = blockIdx.x * 4 + wave;
    if (n >= N) return;
    int h = lane >> 4;
    float adn = ad_[(size_t)n * 4 + h];
    int beg = off[n], end = off[n + 1];
    float acc0 = 0.f, acc1 = 0.f, accd = 0.f;
    for (int p = beg; p < end; ++p) {
        int src = csr_src[p];
        float al = LEAKY(as_[(size_t)src * 4 + h] + adn);
        float ex = __expf(al);
        float2 v = *(const float2*)(hx + (size_t)src * 128 + lane * 2);
        acc0 += ex * v.x; acc1 += ex * v.y; accd += ex;
    }
    float aln = LEAKY(as_[(size_t)n * 4 + h] + adn);
    float exl = __expf(aln);
    float2 vn = *(const float2*)(hx + (size_t)n * 128 + lane * 2);
    float inv = 1.f / (accd + exl);
    float o0 = (acc0 + exl * vn.x) * inv + b[lane * 2 + 0];
    float o1 = (acc1 + exl * vn.y) * inv + b[lane * 2 + 1];
    float2 r; r.x = fmaxf(o0, 0.f); r.y = fmaxf(o1, 0.f);
    *(float2*)(out + (size_t)n * 128 + lane * 2) = r;
}

// ---------------- classifier + log_softmax: wave per node ----------------
__global__ void k_cls(const float* __restrict__ h3, const float* __restrict__ Wc1,
                      const float* __restrict__ bc1, const float* __restrict__ Wc2,
                      const float* __restrict__ bc2, float* __restrict__ out, int N) {
    __shared__ float hs[4 * 128];
    int tid = threadIdx.x;
    int nb = blockIdx.x * 4;
    for (int i = tid; i < 512; i += 256) {
        int n = nb + (i >> 7);
        hs[i] = (n < N) ? h3[(size_t)n * 128 + (i & 127)] : 0.f;
    }
    __syncthreads();
    int wave = tid >> 6, lane = tid & 63;
    int n = nb + wave;
    if (n >= N) return;
    const float* hr = hs + wave * 128;
    float t = bc1[lane];
    for (int k = 0; k < 128; ++k) t += hr[k] * Wc1[k * 64 + lane];
    t = fmaxf(t, 0.f);
    float p[5];
    #pragma unroll
    for (int c = 0; c < 5; ++c) p[c] = t * Wc2[lane * 5 + c];
    #pragma unroll
    for (int m = 1; m < 64; m <<= 1) {
        #pragma unroll
        for (int c = 0; c < 5; ++c) p[c] += __shfl_xor(p[c], m, 64);
    }
    if (lane == 0) {
        float l[5], mx = -1e30f;
        #pragma unroll
        for (int c = 0; c < 5; ++c) { l[c] = p[c] + bc2[c]; mx = fmaxf(mx, l[c]); }
        float s = 0.f;
        #pragma unroll
        for (int c = 0; c < 5; ++c) s += __expf(l[c] - mx);
        float lse = mx + __logf(s);
        #pragma unroll
        for (int c = 0; c < 5; ++c) out[(size_t)n * 5 + c] = l[c] - lse;
    }
}

extern "C" void kernel_launch(void* const* d_in, const int* in_sizes, int n_in,
                              void* d_out, int out_size, void* d_ws, size_t ws_size,
                              hipStream_t stream) {
    const float* x    = (const float*)d_in[0];
    const int*   ei   = (const int*)d_in[1];
    const float* attr = (const float*)d_in[2];
    const int*   mt   = (const int*)d_in[3];
    const int*   mg   = (const int*)d_in[4];
    const int*   mp   = (const int*)d_in[5];
    const float* Wf   = (const float*)d_in[24];
    const float* bf   = (const float*)d_in[25];
    const float* W2   = (const float*)d_in[26];
    const float* a2s  = (const float*)d_in[27];
    const float* a2d  = (const float*)d_in[28];
    const float* b2   = (const float*)d_in[29];
    const float* W3   = (const float*)d_in[30];
    const float* a3s  = (const float*)d_in[31];
    const float* a3d  = (const float*)d_in[32];
    const float* b3   = (const float*)d_in[33];
    const float* Wc1  = (const float*)d_in[34];
    const float* bc1  = (const float*)d_in[35];
    const float* Wc2  = (const float*)d_in[36];
    const float* bc2  = (const float*)d_in[37];

    int N = in_sizes[0];
    int E = in_sizes[1] / 2;

    // workspace carve (aligned to 256B)
    char* w = (char*)d_ws;
    auto alloc = [&](size_t bytes) {
        char* p = w;
        w += (bytes + 255) & ~(size_t)255;
        return p;
    };
    int* off      = (int*)alloc((size_t)(N + 1) * 4);
    int* cursor   = (int*)alloc((size_t)N * 4);
    int* deg      = (int*)alloc((size_t)N * 4);
    int* partials = (int*)alloc(1024 * 4);
    int* csr_src  = (int*)alloc((size_t)E * 4);
    ConstBuf* cb  = (ConstBuf*)alloc(sizeof(ConstBuf));
    float* S      = (float*)alloc((size_t)N * 12 * 4);
    float* as_    = (float*)alloc((size_t)N * 4 * 4);
    float* ad_    = (float*)alloc((size_t)N * 4 * 4);
    float* bufA   = (float*)alloc((size_t)N * 128 * 4);
    float* bufB   = (float*)alloc((size_t)E * 4 * 4 > (size_t)N * 128 * 4
                                  ? (size_t)E * 4 * 4 : (size_t)N * 128 * 4);
    float4* rec   = (float4*)bufB; // rec dies before k_mm128 first writes bufB

    PreArgs pa;
    for (int b = 0; b < 3; ++b) {
        pa.br[b].W   = (const float*)d_in[6 + b * 6 + 0];
        pa.br[b].as_ = (const float*)d_in[6 + b * 6 + 1];
        pa.br[b].ad_ = (const float*)d_in[6 + b * 6 + 2];
        pa.br[b].ae  = (const float*)d_in[6 + b * 6 + 3];
        pa.br[b].We  = (const float*)d_in[6 + b * 6 + 4];
        pa.br[b].b   = (const float*)d_in[6 + b * 6 + 5];
    }
    pa.Wf = Wf; pa.bf = bf; pa.cb = cb;

    int total = N + 1;
    int nScanBlocks = (total + SCAN_EPB - 1) / SCAN_EPB;

    hipMemsetAsync(deg, 0, (size_t)N * 4, stream);
    hipLaunchKernelGGL(k_precompute, dim3(1), dim3(256), 0, stream, pa);
    int gE = (E + 255) / 256;
    hipLaunchKernelGGL(k_count, dim3(gE), dim3(256), 0, stream, ei, E, deg);
    hipLaunchKernelGGL(k_scan1, dim3(nScanBlocks), dim3(256), 0, stream, deg, off, partials, total);
    hipLaunchKernelGGL(k_scan2, dim3(1), dim3(256), 0, stream, partials, nScanBlocks);
    hipLaunchKernelGGL(k_scan3, dim3((total + 255) / 256), dim3(256), 0, stream,
                       off, partials, cursor, total);
    hipLaunchKernelGGL(k_scatter, dim3(gE), dim3(256), 0, stream,
                       ei, attr, mt, mg, mp, E, cursor, csr_src, rec);
    hipLaunchKernelGGL(k_branch, dim3((N + 255) / 256), dim3(256), 0, stream,
                       x, off, csr_src, rec, cb, S, N);
    hipLaunchKernelGGL(k_fuse, dim3(((size_t)N * 128 + 255) / 256), dim3(256), 0, stream,
                       S, cb, bufA, N);
    // conv2: hx2 = h @ W2 -> bufB; aggregate -> h2 in bufA
    hipLaunchKernelGGL(k_mm128, dim3((N + 7) / 8), dim3(128), 0, stream, bufA, W2, bufB, N);
    hipLaunchKernelGGL(k_scores, dim3(((size_t)N * 4 + 255) / 256), dim3(256), 0, stream,
                       bufB, a2s, a2d, as_, ad_, N);
    hipLaunchKernelGGL(k_gatagg, dim3((N + 3) / 4), dim3(256), 0, stream,
                       bufB, as_, ad_, b2, off, csr_src, bufA, N);
    // conv3: hx3 = h2 @ W3 -> bufB; aggregate -> h3 in bufA
    hipLaunchKernelGGL(k_mm128, dim3((N + 7) / 8), dim3(128), 0, stream, bufA, W3, bufB, N);
    hipLaunchKernelGGL(k_scores, dim3(((size_t)N * 4 + 255) / 256), dim3(256), 0, stream,
                       bufB, a3s, a3d, as_, ad_, N);
    hipLaunchKernelGGL(k_gatagg, dim3((N + 3) / 4), dim3(256), 0, stream,
                       bufB, as_, ad_, b3, off, csr_src, bufA, N);
    // classifier
    hipLaunchKernelGGL(k_cls, dim3((N + 3) / 4), dim3(256), 0, stream,
                       bufA, Wc1, bc1, Wc2, bc2, (float*)d_out, N);
}

// Round 3
// 598.801 us; speedup vs baseline: 1.2927x; 1.0519x over previous
//
#include <hip/hip_runtime.h>
#include <hip/hip_bf16.h>

#define LEAKY(v) ((v) > 0.f ? (v) : 0.2f * (v))

__device__ __forceinline__ unsigned short f_to_bf16(float f) {
    union { float f; unsigned int i; } v; v.f = f;
    unsigned int x = v.i;
    return (unsigned short)((x + 0x7fffu + ((x >> 16) & 1u)) >> 16);
}

__device__ __forceinline__ float2 bf2_to_f2(unsigned int u) {
    union { unsigned int i; float f; } a, b;
    a.i = (u & 0xffffu) << 16;
    b.i = u & 0xffff0000u;
    float2 r; r.x = a.f; r.y = b.f;
    return r;
}

struct ConstBuf {
    float ws[3][4];      // dot(W[h,:], a_s[h,:])
    float wd[3][4];      // dot(W[h,:], a_d[h,:])
    float M[3][3][4];    // [branch][attr_k][head]
    float G[12][128];    // folded branch-W through Wf
    float bias2[128];    // bf + concat-bias through Wf
};
#define CB_FLOATS 1724   // 12+12+36+1536+128

struct BranchW { const float *W, *as_, *ad_, *ae, *We, *b; };
struct PreArgs { BranchW br[3]; const float *Wf, *bf; ConstBuf* cb; };

// ---------------- precompute folded weight constants (1 block) ----------------
__global__ void k_precompute(PreArgs A) {
    int t = threadIdx.x; // 256 threads
    if (t < 24) {
        int b = t / 8, r = t % 8, h = r & 3; bool isd = r >= 4;
        const float* a = isd ? A.br[b].ad_ : A.br[b].as_;
        float s = 0.f;
        for (int c = 0; c < 16; ++c) s += A.br[b].W[h * 16 + c] * a[h * 16 + c];
        if (isd) A.cb->wd[b][h] = s; else A.cb->ws[b][h] = s;
    }
    if (t >= 32 && t < 68) {
        int id = t - 32, b = id / 12, k = (id % 12) / 4, h = id & 3;
        float s = 0.f;
        for (int c = 0; c < 16; ++c) s += A.br[b].We[k * 64 + h * 16 + c] * A.br[b].ae[h * 16 + c];
        A.cb->M[b][k][h] = s;
    }
    if (t >= 128) {
        int j = t - 128;
        float s = A.bf[j];
        for (int b = 0; b < 3; ++b)
            for (int i = 0; i < 64; ++i)
                s += A.br[b].b[i] * A.Wf[(b * 64 + i) * 128 + j];
        A.cb->bias2[j] = s;
    }
    for (int id = t; id < 1536; id += 256) {
        int r = id >> 7, j = id & 127, b = r >> 2, h = r & 3;
        float s = 0.f;
        for (int c = 0; c < 16; ++c)
            s += A.br[b].W[h * 16 + c] * A.Wf[(b * 64 + h * 16 + c) * 128 + j];
        A.cb->G[r][j] = s;
    }
}

// ---------------- CSR build ----------------
__global__ void k_count(const int* __restrict__ ei, int E, int* __restrict__ deg) {
    int e = blockIdx.x * blockDim.x + threadIdx.x;
    if (e < E) atomicAdd(&deg[ei[E + e]], 1);
}

#define SCAN_EPB 2048

__global__ void k_scan1(const int* __restrict__ deg, int* __restrict__ off,
                        int* __restrict__ partials, int total) {
    __shared__ int sd[256];
    int t = threadIdx.x;
    int base = blockIdx.x * SCAN_EPB + t * 8;
    int v[8];
    int s = 0;
    #pragma unroll
    for (int i = 0; i < 8; ++i) {
        int idx = base + i;
        v[i] = (idx < total - 1) ? deg[idx] : 0;
        s += v[i];
    }
    sd[t] = s;
    __syncthreads();
    #pragma unroll
    for (int ofs = 1; ofs < 256; ofs <<= 1) {
        int u = (t >= ofs) ? sd[t - ofs] : 0;
        __syncthreads();
        sd[t] += u;
        __syncthreads();
    }
    if (t == 255) partials[blockIdx.x] = sd[255];
    int run = sd[t] - s;
    #pragma unroll
    for (int i = 0; i < 8; ++i) {
        int idx = base + i;
        if (idx < total) off[idx] = run;
        run += v[i];
    }
}

__global__ void k_scan2(int* __restrict__ partials, int nb) {
    __shared__ int sd[256];
    int t = threadIdx.x;
    int v = (t < nb) ? partials[t] : 0;
    sd[t] = v;
    __syncthreads();
    #pragma unroll
    for (int ofs = 1; ofs < 256; ofs <<= 1) {
        int u = (t >= ofs) ? sd[t - ofs] : 0;
        __syncthreads();
        sd[t] += u;
        __syncthreads();
    }
    if (t < nb) partials[t] = sd[t] - v;
}

__global__ void k_scan3(int* __restrict__ off, const int* __restrict__ partials,
                        int* __restrict__ cursor, int total) {
    int idx = blockIdx.x * blockDim.x + threadIdx.x;
    if (idx < total) {
        int v = off[idx] + partials[idx / SCAN_EPB];
        off[idx] = v;
        if (idx < total - 1) cursor[idx] = v;
    }
}

// scatter edges into CSR order, packing attr + mask bits per edge
__global__ void k_scatter(const int* __restrict__ ei, const float* __restrict__ attr,
                          const int* __restrict__ mt, const int* __restrict__ mg,
                          const int* __restrict__ mp, int E, int* __restrict__ cursor,
                          int* __restrict__ csr_src, float4* __restrict__ rec) {
    int e = blockIdx.x * blockDim.x + threadIdx.x;
    if (e < E) {
        int d = ei[E + e];
        int p = atomicAdd(&cursor[d], 1);
        csr_src[p] = ei[e];
        float4 r;
        r.x = attr[e * 3 + 0];
        r.y = attr[e * 3 + 1];
        r.z = attr[e * 3 + 2];
        int bits = (mt[e] != 0 ? 1 : 0) | (mg[e] != 0 ? 2 : 0) | (mp[e] != 0 ? 4 : 0);
        r.w = __int_as_float(bits);
        rec[p] = r;
    }
}

// ------- branch GATs + fusion layer: 16 lanes per node -> h1[N,128] ---------
__global__ void k_branch(const float* __restrict__ x, const int* __restrict__ off,
                         const int* __restrict__ csr_src, const float4* __restrict__ rec,
                         const ConstBuf* __restrict__ cb, float* __restrict__ h1, int N) {
    __shared__ float sc[CB_FLOATS]; // ws|wd|M (60), G (1536), bias2 (128)
    for (int i = threadIdx.x; i < CB_FLOATS; i += 256) sc[i] = ((const float*)cb)[i];
    __syncthreads();
    int g = threadIdx.x >> 4, l = threadIdx.x & 15;
    int n = blockIdx.x * 16 + g;
    if (n >= N) return;

    float num[12], den[12], asum[9], cnt[3];
    #pragma unroll
    for (int i = 0; i < 12; ++i) { num[i] = 0.f; den[i] = 0.f; }
    #pragma unroll
    for (int i = 0; i < 9; ++i) asum[i] = 0.f;
    cnt[0] = cnt[1] = cnt[2] = 0.f;

    float xn = x[n];
    int beg = off[n], end = off[n + 1];
    for (int p = beg + l; p < end; p += 16) {
        int src = csr_src[p];
        float4 r = rec[p];
        float xs = x[src];
        float a0 = r.x, a1 = r.y, a2 = r.z;
        int bits = __float_as_int(r.w);
        #pragma unroll
        for (int b = 0; b < 3; ++b) {
            if ((bits >> b) & 1) {
                cnt[b] += 1.f;
                asum[b * 3 + 0] += a0; asum[b * 3 + 1] += a1; asum[b * 3 + 2] += a2;
                #pragma unroll
                for (int h = 0; h < 4; ++h) {
                    float al = xs * sc[b * 4 + h] + xn * sc[12 + b * 4 + h]
                             + a0 * sc[24 + b * 12 + 0 + h]
                             + a1 * sc[24 + b * 12 + 4 + h]
                             + a2 * sc[24 + b * 12 + 8 + h];
                    al = LEAKY(al);
                    float ex = __expf(al);
                    den[b * 4 + h] += ex;
                    num[b * 4 + h] += ex * xs;
                }
            }
        }
    }
    // butterfly reduce over the 16-lane group (masks <16 stay in-group)
    #pragma unroll
    for (int m = 1; m < 16; m <<= 1) {
        #pragma unroll
        for (int i = 0; i < 12; ++i) {
            num[i] += __shfl_xor(num[i], m, 64);
            den[i] += __shfl_xor(den[i], m, 64);
        }
        #pragma unroll
        for (int i = 0; i < 9; ++i) asum[i] += __shfl_xor(asum[i], m, 64);
        #pragma unroll
        for (int i = 0; i < 3; ++i) cnt[i] += __shfl_xor(cnt[i], m, 64);
    }
    // per-node softmax epilogue (computed redundantly on all 16 lanes)
    float S[12];
    #pragma unroll
    for (int b = 0; b < 3; ++b) {
        float inv = 1.f / fmaxf(cnt[b], 1.f);
        float l0 = asum[b * 3 + 0] * inv, l1 = asum[b * 3 + 1] * inv, l2 = asum[b * 3 + 2] * inv;
        #pragma unroll
        for (int h = 0; h < 4; ++h) {
            float lp = xn * (sc[b * 4 + h] + sc[12 + b * 4 + h])
                     + l0 * sc[24 + b * 12 + 0 + h]
                     + l1 * sc[24 + b * 12 + 4 + h]
                     + l2 * sc[24 + b * 12 + 8 + h];
            lp = LEAKY(lp);
            float exl = __expf(lp);
            float sden = den[b * 4 + h] + exl;
            S[b * 4 + h] = (num[b * 4 + h] + exl * xn) / sden;
        }
    }
    // fused h1 = relu(S @ G + bias2): each lane -> 8 columns
    int jb = l * 8;
    float o[8];
    #pragma unroll
    for (int q = 0; q < 8; ++q) {
        int j = jb + q;
        float a = sc[60 + 1536 + j];
        #pragma unroll
        for (int k = 0; k < 12; ++k) a += S[k] * sc[60 + k * 128 + j];
        o[q] = fmaxf(a, 0.f);
    }
    float4* dst = (float4*)(h1 + (size_t)n * 128 + jb);
    dst[0] = make_float4(o[0], o[1], o[2], o[3]);
    dst[1] = make_float4(o[4], o[5], o[6], o[7]);
}

// ---- [N,128]@[128,128] -> bf16 hx table + fused attention scores ----
__global__ void k_mm128s(const float* __restrict__ A, const float* __restrict__ W,
                         const float* __restrict__ a_s, const float* __restrict__ a_d,
                         unsigned short* __restrict__ hxb, float* __restrict__ as_,
                         float* __restrict__ ad_, int N) {
    __shared__ float As[8 * 128];
    int j = threadIdx.x; // 128 threads
    int n0 = blockIdx.x * 8;
    #pragma unroll
    for (int i = 0; i < 8; ++i) {
        int n = n0 + i;
        As[i * 128 + j] = (n < N) ? A[(size_t)n * 128 + j] : 0.f;
    }
    __syncthreads();
    float acc[8] = {0.f, 0.f, 0.f, 0.f, 0.f, 0.f, 0.f, 0.f};
    for (int k = 0; k < 128; ++k) {
        float wv = W[k * 128 + j];
        #pragma unroll
        for (int i = 0; i < 8; ++i) acc[i] += As[i * 128 + k] * wv;
    }
    float asj = a_s[j], adj = a_d[j];
    int h = j >> 5;
    #pragma unroll
    for (int i = 0; i < 8; ++i) {
        int n = n0 + i;
        if (n < N) hxb[(size_t)n * 128 + j] = f_to_bf16(acc[i]);
        float vs = acc[i] * asj, vd = acc[i] * adj;
        #pragma unroll
        for (int m = 1; m < 32; m <<= 1) {
            vs += __shfl_xor(vs, m, 64);
            vd += __shfl_xor(vd, m, 64);
        }
        if ((j & 31) == 0 && n < N) {
            as_[(size_t)n * 4 + h] = vs;
            ad_[(size_t)n * 4 + h] = vd;
        }
    }
}

// ---------------- GAT aggregation (conv2/conv3): wave per node, bf16 rows ----
__global__ void k_gatagg(const unsigned short* __restrict__ hxb, const float* __restrict__ as_,
                         const float* __restrict__ ad_, const float* __restrict__ b,
                         const int* __restrict__ off, const int* __restrict__ csr_src,
                         float* __restrict__ out, int N) {
    int wave = threadIdx.x >> 6, lane = threadIdx.x & 63;
    int n = blockIdx.x * 4 + wave;
    if (n >= N) return;
    int h = lane >> 4;
    float adn = ad_[(size_t)n * 4 + h];
    int beg = off[n], end = off[n + 1];
    float acc0 = 0.f, acc1 = 0.f, accd = 0.f;
    for (int p = beg; p < end; ++p) {
        int src = csr_src[p];
        float al = LEAKY(as_[(size_t)src * 4 + h] + adn);
        float ex = __expf(al);
        unsigned int u = *(const unsigned int*)(hxb + (size_t)src * 128 + lane * 2);
        float2 v = bf2_to_f2(u);
        acc0 += ex * v.x; acc1 += ex * v.y; accd += ex;
    }
    float aln = LEAKY(as_[(size_t)n * 4 + h] + adn);
    float exl = __expf(aln);
    unsigned int un = *(const unsigned int*)(hxb + (size_t)n * 128 + lane * 2);
    float2 vn = bf2_to_f2(un);
    float inv = 1.f / (accd + exl);
    float o0 = (acc0 + exl * vn.x) * inv + b[lane * 2 + 0];
    float o1 = (acc1 + exl * vn.y) * inv + b[lane * 2 + 1];
    float2 r; r.x = fmaxf(o0, 0.f); r.y = fmaxf(o1, 0.f);
    *(float2*)(out + (size_t)n * 128 + lane * 2) = r;
}

// ---------------- classifier + log_softmax: wave per node ----------------
__global__ void k_cls(const float* __restrict__ h3, const float* __restrict__ Wc1,
                      const float* __restrict__ bc1, const float* __restrict__ Wc2,
                      const float* __restrict__ bc2, float* __restrict__ out, int N) {
    __shared__ float hs[4 * 128];
    int tid = threadIdx.x;
    int nb = blockIdx.x * 4;
    for (int i = tid; i < 512; i += 256) {
        int n = nb + (i >> 7);
        hs[i] = (n < N) ? h3[(size_t)n * 128 + (i & 127)] : 0.f;
    }
    __syncthreads();
    int wave = tid >> 6, lane = tid & 63;
    int n = nb + wave;
    if (n >= N) return;
    const float* hr = hs + wave * 128;
    float t = bc1[lane];
    for (int k = 0; k < 128; ++k) t += hr[k] * Wc1[k * 64 + lane];
    t = fmaxf(t, 0.f);
    float p[5];
    #pragma unroll
    for (int c = 0; c < 5; ++c) p[c] = t * Wc2[lane * 5 + c];
    #pragma unroll
    for (int m = 1; m < 64; m <<= 1) {
        #pragma unroll
        for (int c = 0; c < 5; ++c) p[c] += __shfl_xor(p[c], m, 64);
    }
    if (lane == 0) {
        float l[5], mx = -1e30f;
        #pragma unroll
        for (int c = 0; c < 5; ++c) { l[c] = p[c] + bc2[c]; mx = fmaxf(mx, l[c]); }
        float s = 0.f;
        #pragma unroll
        for (int c = 0; c < 5; ++c) s += __expf(l[c] - mx);
        float lse = mx + __logf(s);
        #pragma unroll
        for (int c = 0; c < 5; ++c) out[(size_t)n * 5 + c] = l[c] - lse;
    }
}

extern "C" void kernel_launch(void* const* d_in, const int* in_sizes, int n_in,
                              void* d_out, int out_size, void* d_ws, size_t ws_size,
                              hipStream_t stream) {
    const float* x    = (const float*)d_in[0];
    const int*   ei   = (const int*)d_in[1];
    const float* attr = (const float*)d_in[2];
    const int*   mt   = (const int*)d_in[3];
    const int*   mg   = (const int*)d_in[4];
    const int*   mp   = (const int*)d_in[5];
    const float* Wf   = (const float*)d_in[24];
    const float* bf   = (const float*)d_in[25];
    const float* W2   = (const float*)d_in[26];
    const float* a2s  = (const float*)d_in[27];
    const float* a2d  = (const float*)d_in[28];
    const float* b2   = (const float*)d_in[29];
    const float* W3   = (const float*)d_in[30];
    const float* a3s  = (const float*)d_in[31];
    const float* a3d  = (const float*)d_in[32];
    const float* b3   = (const float*)d_in[33];
    const float* Wc1  = (const float*)d_in[34];
    const float* bc1  = (const float*)d_in[35];
    const float* Wc2  = (const float*)d_in[36];
    const float* bc2  = (const float*)d_in[37];

    int N = in_sizes[0];
    int E = in_sizes[1] / 2;

    char* w = (char*)d_ws;
    auto alloc = [&](size_t bytes) {
        char* p = w;
        w += (bytes + 255) & ~(size_t)255;
        return p;
    };
    int* off      = (int*)alloc((size_t)(N + 1) * 4);
    int* cursor   = (int*)alloc((size_t)N * 4);
    int* deg      = (int*)alloc((size_t)N * 4);
    int* partials = (int*)alloc(1024 * 4);
    int* csr_src  = (int*)alloc((size_t)E * 4);
    ConstBuf* cb  = (ConstBuf*)alloc(sizeof(ConstBuf));
    float* as_    = (float*)alloc((size_t)N * 4 * 4);
    float* ad_    = (float*)alloc((size_t)N * 4 * 4);
    float* bufA   = (float*)alloc((size_t)N * 128 * 4);
    // rec (E*16 B) and hxb (N*256 B) alias: rec dies at k_branch, hxb born at k_mm128s
    size_t recB   = (size_t)E * 16, hxbB = (size_t)N * 256;
    char* shared2 = alloc(recB > hxbB ? recB : hxbB);
    float4* rec   = (float4*)shared2;
    unsigned short* hxb = (unsigned short*)shared2;

    PreArgs pa;
    for (int b = 0; b < 3; ++b) {
        pa.br[b].W   = (const float*)d_in[6 + b * 6 + 0];
        pa.br[b].as_ = (const float*)d_in[6 + b * 6 + 1];
        pa.br[b].ad_ = (const float*)d_in[6 + b * 6 + 2];
        pa.br[b].ae  = (const float*)d_in[6 + b * 6 + 3];
        pa.br[b].We  = (const float*)d_in[6 + b * 6 + 4];
        pa.br[b].b   = (const float*)d_in[6 + b * 6 + 5];
    }
    pa.Wf = Wf; pa.bf = bf; pa.cb = cb;

    int total = N + 1;
    int nScanBlocks = (total + SCAN_EPB - 1) / SCAN_EPB;

    hipMemsetAsync(deg, 0, (size_t)N * 4, stream);
    hipLaunchKernelGGL(k_precompute, dim3(1), dim3(256), 0, stream, pa);
    int gE = (E + 255) / 256;
    hipLaunchKernelGGL(k_count, dim3(gE), dim3(256), 0, stream, ei, E, deg);
    hipLaunchKernelGGL(k_scan1, dim3(nScanBlocks), dim3(256), 0, stream, deg, off, partials, total);
    hipLaunchKernelGGL(k_scan2, dim3(1), dim3(256), 0, stream, partials, nScanBlocks);
    hipLaunchKernelGGL(k_scan3, dim3((total + 255) / 256), dim3(256), 0, stream,
                       off, partials, cursor, total);
    hipLaunchKernelGGL(k_scatter, dim3(gE), dim3(256), 0, stream,
                       ei, attr, mt, mg, mp, E, cursor, csr_src, rec);
    hipLaunchKernelGGL(k_branch, dim3((N + 15) / 16), dim3(256), 0, stream,
                       x, off, csr_src, rec, cb, bufA, N);
    // conv2
    hipLaunchKernelGGL(k_mm128s, dim3((N + 7) / 8), dim3(128), 0, stream,
                       bufA, W2, a2s, a2d, hxb, as_, ad_, N);
    hipLaunchKernelGGL(k_gatagg, dim3((N + 3) / 4), dim3(256), 0, stream,
                       hxb, as_, ad_, b2, off, csr_src, bufA, N);
    // conv3
    hipLaunchKernelGGL(k_mm128s, dim3((N + 7) / 8), dim3(128), 0, stream,
                       bufA, W3, a3s, a3d, hxb, as_, ad_, N);
    hipLaunchKernelGGL(k_gatagg, dim3((N + 3) / 4), dim3(256), 0, stream,
                       hxb, as_, ad_, b3, off, csr_src, bufA, N);
    // classifier
    hipLaunchKernelGGL(k_cls, dim3((N + 3) / 4), dim3(256), 0, stream,
                       bufA, Wc1, bc1, Wc2, bc2, (float*)d_out, N);
}

// Round 4
// 504.965 us; speedup vs baseline: 1.5329x; 1.1858x over previous
//
#include <hip/hip_runtime.h>
#include <hip/hip_bf16.h>

#define LEAKY(v) ((v) > 0.f ? (v) : 0.2f * (v))

__device__ __forceinline__ unsigned short f_to_bf16(float f) {
    union { float f; unsigned int i; } v; v.f = f;
    unsigned int x = v.i;
    return (unsigned short)((x + 0x7fffu + ((x >> 16) & 1u)) >> 16);
}

__device__ __forceinline__ float2 bf2_to_f2(unsigned int u) {
    union { unsigned int i; float f; } a, b;
    a.i = (u & 0xffffu) << 16;
    b.i = u & 0xffff0000u;
    float2 r; r.x = a.f; r.y = b.f;
    return r;
}

struct ConstBuf {
    float ws[3][4];      // dot(W[h,:], a_s[h,:])
    float wd[3][4];      // dot(W[h,:], a_d[h,:])
    float M[3][3][4];    // [branch][attr_k][head]
    float G[12][128];    // folded branch-W through Wf
    float bias2[128];    // bf + concat-bias through Wf
};
#define CB_FLOATS 1724   // 12+12+36+1536+128

struct BranchW { const float *W, *as_, *ad_, *ae, *We, *b; };
struct PreArgs { BranchW br[3]; const float *Wf, *bf; ConstBuf* cb; };

// ---------------- precompute folded weight constants (1 block) ----------------
__global__ void k_precompute(PreArgs A) {
    int t = threadIdx.x; // 256 threads
    if (t < 24) {
        int b = t / 8, r = t % 8, h = r & 3; bool isd = r >= 4;
        const float* a = isd ? A.br[b].ad_ : A.br[b].as_;
        float s = 0.f;
        for (int c = 0; c < 16; ++c) s += A.br[b].W[h * 16 + c] * a[h * 16 + c];
        if (isd) A.cb->wd[b][h] = s; else A.cb->ws[b][h] = s;
    }
    if (t >= 32 && t < 68) {
        int id = t - 32, b = id / 12, k = (id % 12) / 4, h = id & 3;
        float s = 0.f;
        for (int c = 0; c < 16; ++c) s += A.br[b].We[k * 64 + h * 16 + c] * A.br[b].ae[h * 16 + c];
        A.cb->M[b][k][h] = s;
    }
    if (t >= 128) {
        int j = t - 128;
        float s = A.bf[j];
        for (int b = 0; b < 3; ++b)
            for (int i = 0; i < 64; ++i)
                s += A.br[b].b[i] * A.Wf[(b * 64 + i) * 128 + j];
        A.cb->bias2[j] = s;
    }
    for (int id = t; id < 1536; id += 256) {
        int r = id >> 7, j = id & 127, b = r >> 2, h = r & 3;
        float s = 0.f;
        for (int c = 0; c < 16; ++c)
            s += A.br[b].W[h * 16 + c] * A.Wf[(b * 64 + h * 16 + c) * 128 + j];
        A.cb->G[r][j] = s;
    }
}

// ---------------- CSR build ----------------
__global__ void k_count(const int* __restrict__ ei, int E, int* __restrict__ deg) {
    int e = blockIdx.x * blockDim.x + threadIdx.x;
    if (e < E) atomicAdd(&deg[ei[E + e]], 1);
}

#define SCAN_EPB 2048

__global__ void k_scan1(const int* __restrict__ deg, int* __restrict__ off,
                        int* __restrict__ partials, int total) {
    __shared__ int sd[256];
    int t = threadIdx.x;
    int base = blockIdx.x * SCAN_EPB + t * 8;
    int v[8];
    int s = 0;
    #pragma unroll
    for (int i = 0; i < 8; ++i) {
        int idx = base + i;
        v[i] = (idx < total - 1) ? deg[idx] : 0;
        s += v[i];
    }
    sd[t] = s;
    __syncthreads();
    #pragma unroll
    for (int ofs = 1; ofs < 256; ofs <<= 1) {
        int u = (t >= ofs) ? sd[t - ofs] : 0;
        __syncthreads();
        sd[t] += u;
        __syncthreads();
    }
    if (t == 255) partials[blockIdx.x] = sd[255];
    int run = sd[t] - s;
    #pragma unroll
    for (int i = 0; i < 8; ++i) {
        int idx = base + i;
        if (idx < total) off[idx] = run;
        run += v[i];
    }
}

__global__ void k_scan2(int* __restrict__ partials, int nb) {
    __shared__ int sd[256];
    int t = threadIdx.x;
    int v = (t < nb) ? partials[t] : 0;
    sd[t] = v;
    __syncthreads();
    #pragma unroll
    for (int ofs = 1; ofs < 256; ofs <<= 1) {
        int u = (t >= ofs) ? sd[t - ofs] : 0;
        __syncthreads();
        sd[t] += u;
        __syncthreads();
    }
    if (t < nb) partials[t] = sd[t] - v;
}

__global__ void k_scan3(int* __restrict__ off, const int* __restrict__ partials,
                        int* __restrict__ cursor, int total) {
    int idx = blockIdx.x * blockDim.x + threadIdx.x;
    if (idx < total) {
        int v = off[idx] + partials[idx / SCAN_EPB];
        off[idx] = v;
        if (idx < total - 1) cursor[idx] = v;
    }
}

// scatter edges into CSR order, packing attr + mask bits per edge
__global__ void k_scatter(const int* __restrict__ ei, const float* __restrict__ attr,
                          const int* __restrict__ mt, const int* __restrict__ mg,
                          const int* __restrict__ mp, int E, int* __restrict__ cursor,
                          int* __restrict__ csr_src, float4* __restrict__ rec) {
    int e = blockIdx.x * blockDim.x + threadIdx.x;
    if (e < E) {
        int d = ei[E + e];
        int p = atomicAdd(&cursor[d], 1);
        csr_src[p] = ei[e];
        float4 r;
        r.x = attr[e * 3 + 0];
        r.y = attr[e * 3 + 1];
        r.z = attr[e * 3 + 2];
        int bits = (mt[e] != 0 ? 1 : 0) | (mg[e] != 0 ? 2 : 0) | (mp[e] != 0 ? 4 : 0);
        r.w = __int_as_float(bits);
        rec[p] = r;
    }
}

// ------- branch GATs + fusion layer: 16 lanes per node -> h1[N,128] ---------
__global__ void k_branch(const float* __restrict__ x, const int* __restrict__ off,
                         const int* __restrict__ csr_src, const float4* __restrict__ rec,
                         const ConstBuf* __restrict__ cb, float* __restrict__ h1, int N) {
    __shared__ float sc[CB_FLOATS]; // ws|wd|M (60), G (1536), bias2 (128)
    for (int i = threadIdx.x; i < CB_FLOATS; i += 256) sc[i] = ((const float*)cb)[i];
    __syncthreads();
    int g = threadIdx.x >> 4, l = threadIdx.x & 15;
    int n = blockIdx.x * 16 + g;
    if (n >= N) return;

    float num[12], den[12], asum[9], cnt[3];
    #pragma unroll
    for (int i = 0; i < 12; ++i) { num[i] = 0.f; den[i] = 0.f; }
    #pragma unroll
    for (int i = 0; i < 9; ++i) asum[i] = 0.f;
    cnt[0] = cnt[1] = cnt[2] = 0.f;

    float xn = x[n];
    int beg = off[n], end = off[n + 1];
    for (int p = beg + l; p < end; p += 16) {
        int src = csr_src[p];
        float4 r = rec[p];
        float xs = x[src];
        float a0 = r.x, a1 = r.y, a2 = r.z;
        int bits = __float_as_int(r.w);
        #pragma unroll
        for (int b = 0; b < 3; ++b) {
            if ((bits >> b) & 1) {
                cnt[b] += 1.f;
                asum[b * 3 + 0] += a0; asum[b * 3 + 1] += a1; asum[b * 3 + 2] += a2;
                #pragma unroll
                for (int h = 0; h < 4; ++h) {
                    float al = xs * sc[b * 4 + h] + xn * sc[12 + b * 4 + h]
                             + a0 * sc[24 + b * 12 + 0 + h]
                             + a1 * sc[24 + b * 12 + 4 + h]
                             + a2 * sc[24 + b * 12 + 8 + h];
                    al = LEAKY(al);
                    float ex = __expf(al);
                    den[b * 4 + h] += ex;
                    num[b * 4 + h] += ex * xs;
                }
            }
        }
    }
    // butterfly reduce over the 16-lane group (masks <16 stay in-group)
    #pragma unroll
    for (int m = 1; m < 16; m <<= 1) {
        #pragma unroll
        for (int i = 0; i < 12; ++i) {
            num[i] += __shfl_xor(num[i], m, 64);
            den[i] += __shfl_xor(den[i], m, 64);
        }
        #pragma unroll
        for (int i = 0; i < 9; ++i) asum[i] += __shfl_xor(asum[i], m, 64);
        #pragma unroll
        for (int i = 0; i < 3; ++i) cnt[i] += __shfl_xor(cnt[i], m, 64);
    }
    // per-node softmax epilogue (computed redundantly on all 16 lanes)
    float S[12];
    #pragma unroll
    for (int b = 0; b < 3; ++b) {
        float inv = 1.f / fmaxf(cnt[b], 1.f);
        float l0 = asum[b * 3 + 0] * inv, l1 = asum[b * 3 + 1] * inv, l2 = asum[b * 3 + 2] * inv;
        #pragma unroll
        for (int h = 0; h < 4; ++h) {
            float lp = xn * (sc[b * 4 + h] + sc[12 + b * 4 + h])
                     + l0 * sc[24 + b * 12 + 0 + h]
                     + l1 * sc[24 + b * 12 + 4 + h]
                     + l2 * sc[24 + b * 12 + 8 + h];
            lp = LEAKY(lp);
            float exl = __expf(lp);
            float sden = den[b * 4 + h] + exl;
            S[b * 4 + h] = (num[b * 4 + h] + exl * xn) / sden;
        }
    }
    // fused h1 = relu(S @ G + bias2): each lane -> 8 columns
    int jb = l * 8;
    float o[8];
    #pragma unroll
    for (int q = 0; q < 8; ++q) {
        int j = jb + q;
        float a = sc[60 + 1536 + j];
        #pragma unroll
        for (int k = 0; k < 12; ++k) a += S[k] * sc[60 + k * 128 + j];
        o[q] = fmaxf(a, 0.f);
    }
    float4* dst = (float4*)(h1 + (size_t)n * 128 + jb);
    dst[0] = make_float4(o[0], o[1], o[2], o[3]);
    dst[1] = make_float4(o[4], o[5], o[6], o[7]);
}

// ---- [N,128]@[128,128] -> bf16 hx table + fused attention scores ----
__global__ void k_mm128s(const float* __restrict__ A, const float* __restrict__ W,
                         const float* __restrict__ a_s, const float* __restrict__ a_d,
                         unsigned short* __restrict__ hxb, float* __restrict__ as_,
                         float* __restrict__ ad_, int N) {
    __shared__ float As[8 * 128];
    int j = threadIdx.x; // 128 threads
    int n0 = blockIdx.x * 8;
    #pragma unroll
    for (int i = 0; i < 8; ++i) {
        int n = n0 + i;
        As[i * 128 + j] = (n < N) ? A[(size_t)n * 128 + j] : 0.f;
    }
    __syncthreads();
    float acc[8] = {0.f, 0.f, 0.f, 0.f, 0.f, 0.f, 0.f, 0.f};
    for (int k = 0; k < 128; ++k) {
        float wv = W[k * 128 + j];
        #pragma unroll
        for (int i = 0; i < 8; ++i) acc[i] += As[i * 128 + k] * wv;
    }
    float asj = a_s[j], adj = a_d[j];
    int h = j >> 5;
    #pragma unroll
    for (int i = 0; i < 8; ++i) {
        int n = n0 + i;
        if (n < N) hxb[(size_t)n * 128 + j] = f_to_bf16(acc[i]);
        float vs = acc[i] * asj, vd = acc[i] * adj;
        #pragma unroll
        for (int m = 1; m < 32; m <<= 1) {
            vs += __shfl_xor(vs, m, 64);
            vd += __shfl_xor(vd, m, 64);
        }
        if ((j & 31) == 0 && n < N) {
            as_[(size_t)n * 4 + h] = vs;
            ad_[(size_t)n * 4 + h] = vd;
        }
    }
}

// ------- GAT aggregation (conv2/conv3): wave per node, bf16 rows, unroll-4 ---
__global__ void k_gatagg(const unsigned short* __restrict__ hxb, const float* __restrict__ as_,
                         const float* __restrict__ ad_, const float* __restrict__ b,
                         const int* __restrict__ off, const int* __restrict__ csr_src,
                         float* __restrict__ out, int N) {
    int wave = threadIdx.x >> 6, lane = threadIdx.x & 63;
    int n = blockIdx.x * 4 + wave;
    if (n >= N) return;
    int h = lane >> 4;
    int lofs = lane * 2;
    float adn = ad_[(size_t)n * 4 + h];
    int beg = off[n], end = off[n + 1];
    float acc0 = 0.f, acc1 = 0.f, accd = 0.f;
    int p = beg;
    for (; p + 4 <= end; p += 4) {
        int s0 = csr_src[p + 0];
        int s1 = csr_src[p + 1];
        int s2 = csr_src[p + 2];
        int s3 = csr_src[p + 3];
        float e0 = as_[(size_t)s0 * 4 + h];
        float e1 = as_[(size_t)s1 * 4 + h];
        float e2 = as_[(size_t)s2 * 4 + h];
        float e3 = as_[(size_t)s3 * 4 + h];
        unsigned int u0 = *(const unsigned int*)(hxb + (size_t)s0 * 128 + lofs);
        unsigned int u1 = *(const unsigned int*)(hxb + (size_t)s1 * 128 + lofs);
        unsigned int u2 = *(const unsigned int*)(hxb + (size_t)s2 * 128 + lofs);
        unsigned int u3 = *(const unsigned int*)(hxb + (size_t)s3 * 128 + lofs);
        float x0 = __expf(LEAKY(e0 + adn));
        float x1 = __expf(LEAKY(e1 + adn));
        float x2 = __expf(LEAKY(e2 + adn));
        float x3 = __expf(LEAKY(e3 + adn));
        float2 v0 = bf2_to_f2(u0), v1 = bf2_to_f2(u1), v2 = bf2_to_f2(u2), v3 = bf2_to_f2(u3);
        acc0 += x0 * v0.x + x1 * v1.x + x2 * v2.x + x3 * v3.x;
        acc1 += x0 * v0.y + x1 * v1.y + x2 * v2.y + x3 * v3.y;
        accd += x0 + x1 + x2 + x3;
    }
    for (; p < end; ++p) {
        int src = csr_src[p];
        float al = LEAKY(as_[(size_t)src * 4 + h] + adn);
        float ex = __expf(al);
        unsigned int u = *(const unsigned int*)(hxb + (size_t)src * 128 + lofs);
        float2 v = bf2_to_f2(u);
        acc0 += ex * v.x; acc1 += ex * v.y; accd += ex;
    }
    float aln = LEAKY(as_[(size_t)n * 4 + h] + adn);
    float exl = __expf(aln);
    unsigned int un = *(const unsigned int*)(hxb + (size_t)n * 128 + lofs);
    float2 vn = bf2_to_f2(un);
    float inv = 1.f / (accd + exl);
    float o0 = (acc0 + exl * vn.x) * inv + b[lofs + 0];
    float o1 = (acc1 + exl * vn.y) * inv + b[lofs + 1];
    float2 r; r.x = fmaxf(o0, 0.f); r.y = fmaxf(o1, 0.f);
    *(float2*)(out + (size_t)n * 128 + lofs) = r;
}

// ------- classifier + log_softmax: Wc1 staged in LDS, 4 nodes per wave -------
#define CLS_NPB 16
__global__ void k_cls(const float* __restrict__ h3, const float* __restrict__ Wc1,
                      const float* __restrict__ bc1, const float* __restrict__ Wc2,
                      const float* __restrict__ bc2, float* __restrict__ out, int N) {
    __shared__ float sw[128 * 64];      // 32 KB
    __shared__ float hs[CLS_NPB * 128]; // 8 KB
    int tid = threadIdx.x;
    int nb = blockIdx.x * CLS_NPB;
    for (int i = tid; i < 128 * 64; i += 256) sw[i] = Wc1[i];
    for (int i = tid; i < CLS_NPB * 128; i += 256) {
        int n = nb + (i >> 7);
        hs[i] = (n < N) ? h3[(size_t)n * 128 + (i & 127)] : 0.f;
    }
    __syncthreads();
    int wave = tid >> 6, lane = tid & 63;
    const float* r0 = hs + (wave * 4 + 0) * 128;
    const float* r1 = hs + (wave * 4 + 1) * 128;
    const float* r2 = hs + (wave * 4 + 2) * 128;
    const float* r3 = hs + (wave * 4 + 3) * 128;
    float bl = bc1[lane];
    float t0 = bl, t1 = bl, t2 = bl, t3 = bl;
    for (int k = 0; k < 128; ++k) {
        float wv = sw[k * 64 + lane];
        t0 += r0[k] * wv; t1 += r1[k] * wv; t2 += r2[k] * wv; t3 += r3[k] * wv;
    }
    t0 = fmaxf(t0, 0.f); t1 = fmaxf(t1, 0.f); t2 = fmaxf(t2, 0.f); t3 = fmaxf(t3, 0.f);
    float w2[5];
    #pragma unroll
    for (int c = 0; c < 5; ++c) w2[c] = Wc2[lane * 5 + c];
    float p[4][5];
    #pragma unroll
    for (int c = 0; c < 5; ++c) {
        p[0][c] = t0 * w2[c]; p[1][c] = t1 * w2[c];
        p[2][c] = t2 * w2[c]; p[3][c] = t3 * w2[c];
    }
    #pragma unroll
    for (int m = 1; m < 64; m <<= 1) {
        #pragma unroll
        for (int i = 0; i < 4; ++i)
            #pragma unroll
            for (int c = 0; c < 5; ++c)
                p[i][c] += __shfl_xor(p[i][c], m, 64);
    }
    if (lane == 0) {
        #pragma unroll
        for (int i = 0; i < 4; ++i) {
            int n = nb + wave * 4 + i;
            if (n >= N) continue;
            float l[5], mx = -1e30f;
            #pragma unroll
            for (int c = 0; c < 5; ++c) { l[c] = p[i][c] + bc2[c]; mx = fmaxf(mx, l[c]); }
            float s = 0.f;
            #pragma unroll
            for (int c = 0; c < 5; ++c) s += __expf(l[c] - mx);
            float lse = mx + __logf(s);
            #pragma unroll
            for (int c = 0; c < 5; ++c) out[(size_t)n * 5 + c] = l[c] - lse;
        }
    }
}

extern "C" void kernel_launch(void* const* d_in, const int* in_sizes, int n_in,
                              void* d_out, int out_size, void* d_ws, size_t ws_size,
                              hipStream_t stream) {
    const float* x    = (const float*)d_in[0];
    const int*   ei   = (const int*)d_in[1];
    const float* attr = (const float*)d_in[2];
    const int*   mt   = (const int*)d_in[3];
    const int*   mg   = (const int*)d_in[4];
    const int*   mp   = (const int*)d_in[5];
    const float* Wf   = (const float*)d_in[24];
    const float* bf   = (const float*)d_in[25];
    const float* W2   = (const float*)d_in[26];
    const float* a2s  = (const float*)d_in[27];
    const float* a2d  = (const float*)d_in[28];
    const float* b2   = (const float*)d_in[29];
    const float* W3   = (const float*)d_in[30];
    const float* a3s  = (const float*)d_in[31];
    const float* a3d  = (const float*)d_in[32];
    const float* b3   = (const float*)d_in[33];
    const float* Wc1  = (const float*)d_in[34];
    const float* bc1  = (const float*)d_in[35];
    const float* Wc2  = (const float*)d_in[36];
    const float* bc2  = (const float*)d_in[37];

    int N = in_sizes[0];
    int E = in_sizes[1] / 2;

    char* w = (char*)d_ws;
    auto alloc = [&](size_t bytes) {
        char* p = w;
        w += (bytes + 255) & ~(size_t)255;
        return p;
    };
    int* off      = (int*)alloc((size_t)(N + 1) * 4);
    int* cursor   = (int*)alloc((size_t)N * 4);
    int* deg      = (int*)alloc((size_t)N * 4);
    int* partials = (int*)alloc(1024 * 4);
    int* csr_src  = (int*)alloc((size_t)E * 4);
    ConstBuf* cb  = (ConstBuf*)alloc(sizeof(ConstBuf));
    float* as_    = (float*)alloc((size_t)N * 4 * 4);
    float* ad_    = (float*)alloc((size_t)N * 4 * 4);
    float* bufA   = (float*)alloc((size_t)N * 128 * 4);
    // rec (E*16 B) and hxb (N*256 B) alias: rec dies at k_branch, hxb born at k_mm128s
    size_t recB   = (size_t)E * 16, hxbB = (size_t)N * 256;
    char* shared2 = alloc(recB > hxbB ? recB : hxbB);
    float4* rec   = (float4*)shared2;
    unsigned short* hxb = (unsigned short*)shared2;

    PreArgs pa;
    for (int b = 0; b < 3; ++b) {
        pa.br[b].W   = (const float*)d_in[6 + b * 6 + 0];
        pa.br[b].as_ = (const float*)d_in[6 + b * 6 + 1];
        pa.br[b].ad_ = (const float*)d_in[6 + b * 6 + 2];
        pa.br[b].ae  = (const float*)d_in[6 + b * 6 + 3];
        pa.br[b].We  = (const float*)d_in[6 + b * 6 + 4];
        pa.br[b].b   = (const float*)d_in[6 + b * 6 + 5];
    }
    pa.Wf = Wf; pa.bf = bf; pa.cb = cb;

    int total = N + 1;
    int nScanBlocks = (total + SCAN_EPB - 1) / SCAN_EPB;

    hipMemsetAsync(deg, 0, (size_t)N * 4, stream);
    hipLaunchKernelGGL(k_precompute, dim3(1), dim3(256), 0, stream, pa);
    int gE = (E + 255) / 256;
    hipLaunchKernelGGL(k_count, dim3(gE), dim3(256), 0, stream, ei, E, deg);
    hipLaunchKernelGGL(k_scan1, dim3(nScanBlocks), dim3(256), 0, stream, deg, off, partials, total);
    hipLaunchKernelGGL(k_scan2, dim3(1), dim3(256), 0, stream, partials, nScanBlocks);
    hipLaunchKernelGGL(k_scan3, dim3((total + 255) / 256), dim3(256), 0, stream,
                       off, partials, cursor, total);
    hipLaunchKernelGGL(k_scatter, dim3(gE), dim3(256), 0, stream,
                       ei, attr, mt, mg, mp, E, cursor, csr_src, rec);
    hipLaunchKernelGGL(k_branch, dim3((N + 15) / 16), dim3(256), 0, stream,
                       x, off, csr_src, rec, cb, bufA, N);
    // conv2
    hipLaunchKernelGGL(k_mm128s, dim3((N + 7) / 8), dim3(128), 0, stream,
                       bufA, W2, a2s, a2d, hxb, as_, ad_, N);
    hipLaunchKernelGGL(k_gatagg, dim3((N + 3) / 4), dim3(256), 0, stream,
                       hxb, as_, ad_, b2, off, csr_src, bufA, N);
    // conv3
    hipLaunchKernelGGL(k_mm128s, dim3((N + 7) / 8), dim3(128), 0, stream,
                       bufA, W3, a3s, a3d, hxb, as_, ad_, N);
    hipLaunchKernelGGL(k_gatagg, dim3((N + 3) / 4), dim3(256), 0, stream,
                       hxb, as_, ad_, b3, off, csr_src, bufA, N);
    // classifier
    hipLaunchKernelGGL(k_cls, dim3((N + CLS_NPB - 1) / CLS_NPB), dim3(256), 0, stream,
                       bufA, Wc1, bc1, Wc2, bc2, (float*)d_out, N);
}

// Round 5
// 493.884 us; speedup vs baseline: 1.5673x; 1.0224x over previous
//
#include <hip/hip_runtime.h>
#include <hip/hip_bf16.h>

#define LEAKY(v) ((v) > 0.f ? (v) : 0.2f * (v))

__device__ __forceinline__ unsigned short f_to_bf16(float f) {
    union { float f; unsigned int i; } v; v.f = f;
    unsigned int x = v.i;
    return (unsigned short)((x + 0x7fffu + ((x >> 16) & 1u)) >> 16);
}

__device__ __forceinline__ float2 bf2_to_f2(unsigned int u) {
    union { unsigned int i; float f; } a, b;
    a.i = (u & 0xffffu) << 16;
    b.i = u & 0xffff0000u;
    float2 r; r.x = a.f; r.y = b.f;
    return r;
}

struct ConstBuf {
    float ws[3][4];      // dot(W[h,:], a_s[h,:])
    float wd[3][4];      // dot(W[h,:], a_d[h,:])
    float M[3][3][4];    // [branch][attr_k][head]
    float G[12][128];    // folded branch-W through Wf
    float bias2[128];    // bf + concat-bias through Wf
};
#define CB_FLOATS 1724   // 12+12+36+1536+128

struct BranchW { const float *W, *as_, *ad_, *ae, *We, *b; };
struct PreArgs { BranchW br[3]; const float *Wf, *bf; ConstBuf* cb; };

// ---------------- precompute folded weight constants (1 block) ----------------
__global__ void k_precompute(PreArgs A) {
    int t = threadIdx.x; // 256 threads
    if (t < 24) {
        int b = t / 8, r = t % 8, h = r & 3; bool isd = r >= 4;
        const float* a = isd ? A.br[b].ad_ : A.br[b].as_;
        float s = 0.f;
        for (int c = 0; c < 16; ++c) s += A.br[b].W[h * 16 + c] * a[h * 16 + c];
        if (isd) A.cb->wd[b][h] = s; else A.cb->ws[b][h] = s;
    }
    if (t >= 32 && t < 68) {
        int id = t - 32, b = id / 12, k = (id % 12) / 4, h = id & 3;
        float s = 0.f;
        for (int c = 0; c < 16; ++c) s += A.br[b].We[k * 64 + h * 16 + c] * A.br[b].ae[h * 16 + c];
        A.cb->M[b][k][h] = s;
    }
    if (t >= 128) {
        int j = t - 128;
        float s = A.bf[j];
        for (int b = 0; b < 3; ++b)
            for (int i = 0; i < 64; ++i)
                s += A.br[b].b[i] * A.Wf[(b * 64 + i) * 128 + j];
        A.cb->bias2[j] = s;
    }
    for (int id = t; id < 1536; id += 256) {
        int r = id >> 7, j = id & 127, b = r >> 2, h = r & 3;
        float s = 0.f;
        for (int c = 0; c < 16; ++c)
            s += A.br[b].W[h * 16 + c] * A.Wf[(b * 64 + h * 16 + c) * 128 + j];
        A.cb->G[r][j] = s;
    }
}

// ---------------- CSR build ----------------
__global__ void k_count(const int* __restrict__ ei, int E, int* __restrict__ deg) {
    int e = blockIdx.x * blockDim.x + threadIdx.x;
    if (e < E) atomicAdd(&deg[ei[E + e]], 1);
}

#define SCAN_EPB 2048

__global__ void k_scan1(const int* __restrict__ deg, int* __restrict__ off,
                        int* __restrict__ partials, int total) {
    __shared__ int sd[256];
    int t = threadIdx.x;
    int base = blockIdx.x * SCAN_EPB + t * 8;
    int v[8];
    int s = 0;
    #pragma unroll
    for (int i = 0; i < 8; ++i) {
        int idx = base + i;
        v[i] = (idx < total - 1) ? deg[idx] : 0;
        s += v[i];
    }
    sd[t] = s;
    __syncthreads();
    #pragma unroll
    for (int ofs = 1; ofs < 256; ofs <<= 1) {
        int u = (t >= ofs) ? sd[t - ofs] : 0;
        __syncthreads();
        sd[t] += u;
        __syncthreads();
    }
    if (t == 255) partials[blockIdx.x] = sd[255];
    int run = sd[t] - s;
    #pragma unroll
    for (int i = 0; i < 8; ++i) {
        int idx = base + i;
        if (idx < total) off[idx] = run;
        run += v[i];
    }
}

__global__ void k_scan2(int* __restrict__ partials, int nb) {
    __shared__ int sd[256];
    int t = threadIdx.x;
    int v = (t < nb) ? partials[t] : 0;
    sd[t] = v;
    __syncthreads();
    #pragma unroll
    for (int ofs = 1; ofs < 256; ofs <<= 1) {
        int u = (t >= ofs) ? sd[t - ofs] : 0;
        __syncthreads();
        sd[t] += u;
        __syncthreads();
    }
    if (t < nb) partials[t] = sd[t] - v;
}

__global__ void k_scan3(int* __restrict__ off, const int* __restrict__ partials,
                        int* __restrict__ cursor, int total) {
    int idx = blockIdx.x * blockDim.x + threadIdx.x;
    if (idx < total) {
        int v = off[idx] + partials[idx / SCAN_EPB];
        off[idx] = v;
        if (idx < total - 1) cursor[idx] = v;
    }
}

// scatter edges into CSR order: ONE 16B record per edge
// rec = (a0, a1, a2, bits{src | maskbits<<16})   [src < 2^16]
__global__ void k_scatter(const int* __restrict__ ei, const float* __restrict__ attr,
                          const int* __restrict__ mt, const int* __restrict__ mg,
                          const int* __restrict__ mp, int E, int* __restrict__ cursor,
                          float4* __restrict__ rec) {
    int e = blockIdx.x * blockDim.x + threadIdx.x;
    if (e < E) {
        int d = ei[E + e];
        int p = atomicAdd(&cursor[d], 1);
        float4 r;
        r.x = attr[e * 3 + 0];
        r.y = attr[e * 3 + 1];
        r.z = attr[e * 3 + 2];
        unsigned int bits = (mt[e] != 0 ? 1u : 0u) | (mg[e] != 0 ? 2u : 0u) | (mp[e] != 0 ? 4u : 0u);
        unsigned int packed = (unsigned int)ei[e] | (bits << 16);
        r.w = __int_as_float((int)packed);
        rec[p] = r;
    }
}

// ------- branch GATs + fusion layer: 16 lanes per node -> h1[N,128] ---------
// side-product: writes csr_src[p] (unpacked from rec) for the downstream gatagg
__global__ void k_branch(const float* __restrict__ x, const int* __restrict__ off,
                         const float4* __restrict__ rec, int* __restrict__ csr_src,
                         const ConstBuf* __restrict__ cb, float* __restrict__ h1, int N) {
    __shared__ float sc[CB_FLOATS]; // ws|wd|M (60), G (1536), bias2 (128)
    for (int i = threadIdx.x; i < CB_FLOATS; i += 256) sc[i] = ((const float*)cb)[i];
    __syncthreads();
    int g = threadIdx.x >> 4, l = threadIdx.x & 15;
    int n = blockIdx.x * 16 + g;
    if (n >= N) return;

    float num[12], den[12], asum[9], cnt[3];
    #pragma unroll
    for (int i = 0; i < 12; ++i) { num[i] = 0.f; den[i] = 0.f; }
    #pragma unroll
    for (int i = 0; i < 9; ++i) asum[i] = 0.f;
    cnt[0] = cnt[1] = cnt[2] = 0.f;

    float xn = x[n];
    int beg = off[n], end = off[n + 1];
    for (int p = beg + l; p < end; p += 16) {
        float4 r = rec[p];
        unsigned int packed = (unsigned int)__float_as_int(r.w);
        int src = (int)(packed & 0xffffu);
        unsigned int bits = packed >> 16;
        csr_src[p] = src;
        float xs = x[src];
        float a0 = r.x, a1 = r.y, a2 = r.z;
        #pragma unroll
        for (int b = 0; b < 3; ++b) {
            if ((bits >> b) & 1u) {
                cnt[b] += 1.f;
                asum[b * 3 + 0] += a0; asum[b * 3 + 1] += a1; asum[b * 3 + 2] += a2;
                #pragma unroll
                for (int h = 0; h < 4; ++h) {
                    float al = xs * sc[b * 4 + h] + xn * sc[12 + b * 4 + h]
                             + a0 * sc[24 + b * 12 + 0 + h]
                             + a1 * sc[24 + b * 12 + 4 + h]
                             + a2 * sc[24 + b * 12 + 8 + h];
                    al = LEAKY(al);
                    float ex = __expf(al);
                    den[b * 4 + h] += ex;
                    num[b * 4 + h] += ex * xs;
                }
            }
        }
    }
    // butterfly reduce over the 16-lane group (masks <16 stay in-group)
    #pragma unroll
    for (int m = 1; m < 16; m <<= 1) {
        #pragma unroll
        for (int i = 0; i < 12; ++i) {
            num[i] += __shfl_xor(num[i], m, 64);
            den[i] += __shfl_xor(den[i], m, 64);
        }
        #pragma unroll
        for (int i = 0; i < 9; ++i) asum[i] += __shfl_xor(asum[i], m, 64);
        #pragma unroll
        for (int i = 0; i < 3; ++i) cnt[i] += __shfl_xor(cnt[i], m, 64);
    }
    // per-node softmax epilogue (computed redundantly on all 16 lanes)
    float S[12];
    #pragma unroll
    for (int b = 0; b < 3; ++b) {
        float inv = 1.f / fmaxf(cnt[b], 1.f);
        float l0 = asum[b * 3 + 0] * inv, l1 = asum[b * 3 + 1] * inv, l2 = asum[b * 3 + 2] * inv;
        #pragma unroll
        for (int h = 0; h < 4; ++h) {
            float lp = xn * (sc[b * 4 + h] + sc[12 + b * 4 + h])
                     + l0 * sc[24 + b * 12 + 0 + h]
                     + l1 * sc[24 + b * 12 + 4 + h]
                     + l2 * sc[24 + b * 12 + 8 + h];
            lp = LEAKY(lp);
            float exl = __expf(lp);
            float sden = den[b * 4 + h] + exl;
            S[b * 4 + h] = (num[b * 4 + h] + exl * xn) / sden;
        }
    }
    // fused h1 = relu(S @ G + bias2): each lane -> 8 columns
    int jb = l * 8;
    float o[8];
    #pragma unroll
    for (int q = 0; q < 8; ++q) {
        int j = jb + q;
        float a = sc[60 + 1536 + j];
        #pragma unroll
        for (int k = 0; k < 12; ++k) a += S[k] * sc[60 + k * 128 + j];
        o[q] = fmaxf(a, 0.f);
    }
    float4* dst = (float4*)(h1 + (size_t)n * 128 + jb);
    dst[0] = make_float4(o[0], o[1], o[2], o[3]);
    dst[1] = make_float4(o[4], o[5], o[6], o[7]);
}

// ---- [N,128]@[128,128] -> bf16 hx table + fused attention scores ----
__global__ void k_mm128s(const float* __restrict__ A, const float* __restrict__ W,
                         const float* __restrict__ a_s, const float* __restrict__ a_d,
                         unsigned short* __restrict__ hxb, float* __restrict__ as_,
                         float* __restrict__ ad_, int N) {
    __shared__ float As[8 * 128];
    int j = threadIdx.x; // 128 threads
    int n0 = blockIdx.x * 8;
    #pragma unroll
    for (int i = 0; i < 8; ++i) {
        int n = n0 + i;
        As[i * 128 + j] = (n < N) ? A[(size_t)n * 128 + j] : 0.f;
    }
    __syncthreads();
    float acc[8] = {0.f, 0.f, 0.f, 0.f, 0.f, 0.f, 0.f, 0.f};
    for (int k = 0; k < 128; ++k) {
        float wv = W[k * 128 + j];
        #pragma unroll
        for (int i = 0; i < 8; ++i) acc[i] += As[i * 128 + k] * wv;
    }
    float asj = a_s[j], adj = a_d[j];
    int h = j >> 5;
    #pragma unroll
    for (int i = 0; i < 8; ++i) {
        int n = n0 + i;
        if (n < N) hxb[(size_t)n * 128 + j] = f_to_bf16(acc[i]);
        float vs = acc[i] * asj, vd = acc[i] * adj;
        #pragma unroll
        for (int m = 1; m < 32; m <<= 1) {
            vs += __shfl_xor(vs, m, 64);
            vd += __shfl_xor(vd, m, 64);
        }
        if ((j & 31) == 0 && n < N) {
            as_[(size_t)n * 4 + h] = vs;
            ad_[(size_t)n * 4 + h] = vd;
        }
    }
}

// ------- GAT aggregation (conv2/conv3): wave per node, bf16 rows, 8-wide MLP -
__global__ void k_gatagg(const unsigned short* __restrict__ hxb, const float* __restrict__ as_,
                         const float* __restrict__ ad_, const float* __restrict__ b,
                         const int* __restrict__ off, const int* __restrict__ csr_src,
                         float* __restrict__ out, int N) {
    int wave = threadIdx.x >> 6, lane = threadIdx.x & 63;
    int n = blockIdx.x * 4 + wave;
    if (n >= N) return;
    int h = lane >> 4;
    int lofs = lane * 2;
    float adn = ad_[(size_t)n * 4 + h];
    int beg = off[n], end = off[n + 1];
    float acc0 = 0.f, acc1 = 0.f, accd = 0.f;
    for (int p = beg; p < end; p += 8) {
        int s[8]; float e[8]; unsigned int u[8]; bool valid[8];
        #pragma unroll
        for (int i = 0; i < 8; ++i) {
            valid[i] = (p + i < end);
            int q = valid[i] ? (p + i) : beg;
            s[i] = csr_src[q];
        }
        #pragma unroll
        for (int i = 0; i < 8; ++i) e[i] = as_[(size_t)s[i] * 4 + h];
        #pragma unroll
        for (int i = 0; i < 8; ++i) u[i] = *(const unsigned int*)(hxb + (size_t)s[i] * 128 + lofs);
        #pragma unroll
        for (int i = 0; i < 8; ++i) {
            float ex = valid[i] ? __expf(LEAKY(e[i] + adn)) : 0.f;
            float2 v = bf2_to_f2(u[i]);
            acc0 += ex * v.x; acc1 += ex * v.y; accd += ex;
        }
    }
    float aln = LEAKY(as_[(size_t)n * 4 + h] + adn);
    float exl = __expf(aln);
    unsigned int un = *(const unsigned int*)(hxb + (size_t)n * 128 + lofs);
    float2 vn = bf2_to_f2(un);
    float inv = 1.f / (accd + exl);
    float o0 = (acc0 + exl * vn.x) * inv + b[lofs + 0];
    float o1 = (acc1 + exl * vn.y) * inv + b[lofs + 1];
    float2 r; r.x = fmaxf(o0, 0.f); r.y = fmaxf(o1, 0.f);
    *(float2*)(out + (size_t)n * 128 + lofs) = r;
}

// ------- classifier + log_softmax: Wc1 staged in LDS, 4 nodes per wave -------
#define CLS_NPB 16
__global__ void k_cls(const float* __restrict__ h3, const float* __restrict__ Wc1,
                      const float* __restrict__ bc1, const float* __restrict__ Wc2,
                      const float* __restrict__ bc2, float* __restrict__ out, int N) {
    __shared__ float sw[128 * 64];      // 32 KB
    __shared__ float hs[CLS_NPB * 128]; // 8 KB
    int tid = threadIdx.x;
    int nb = blockIdx.x * CLS_NPB;
    for (int i = tid; i < 128 * 64; i += 256) sw[i] = Wc1[i];
    for (int i = tid; i < CLS_NPB * 128; i += 256) {
        int n = nb + (i >> 7);
        hs[i] = (n < N) ? h3[(size_t)n * 128 + (i & 127)] : 0.f;
    }
    __syncthreads();
    int wave = tid >> 6, lane = tid & 63;
    const float* r0 = hs + (wave * 4 + 0) * 128;
    const float* r1 = hs + (wave * 4 + 1) * 128;
    const float* r2 = hs + (wave * 4 + 2) * 128;
    const float* r3 = hs + (wave * 4 + 3) * 128;
    float bl = bc1[lane];
    float t0 = bl, t1 = bl, t2 = bl, t3 = bl;
    for (int k = 0; k < 128; ++k) {
        float wv = sw[k * 64 + lane];
        t0 += r0[k] * wv; t1 += r1[k] * wv; t2 += r2[k] * wv; t3 += r3[k] * wv;
    }
    t0 = fmaxf(t0, 0.f); t1 = fmaxf(t1, 0.f); t2 = fmaxf(t2, 0.f); t3 = fmaxf(t3, 0.f);
    float w2[5];
    #pragma unroll
    for (int c = 0; c < 5; ++c) w2[c] = Wc2[lane * 5 + c];
    float p[4][5];
    #pragma unroll
    for (int c = 0; c < 5; ++c) {
        p[0][c] = t0 * w2[c]; p[1][c] = t1 * w2[c];
        p[2][c] = t2 * w2[c]; p[3][c] = t3 * w2[c];
    }
    #pragma unroll
    for (int m = 1; m < 64; m <<= 1) {
        #pragma unroll
        for (int i = 0; i < 4; ++i)
            #pragma unroll
            for (int c = 0; c < 5; ++c)
                p[i][c] += __shfl_xor(p[i][c], m, 64);
    }
    if (lane == 0) {
        #pragma unroll
        for (int i = 0; i < 4; ++i) {
            int n = nb + wave * 4 + i;
            if (n >= N) continue;
            float l[5], mx = -1e30f;
            #pragma unroll
            for (int c = 0; c < 5; ++c) { l[c] = p[i][c] + bc2[c]; mx = fmaxf(mx, l[c]); }
            float s = 0.f;
            #pragma unroll
            for (int c = 0; c < 5; ++c) s += __expf(l[c] - mx);
            float lse = mx + __logf(s);
            #pragma unroll
            for (int c = 0; c < 5; ++c) out[(size_t)n * 5 + c] = l[c] - lse;
        }
    }
}

extern "C" void kernel_launch(void* const* d_in, const int* in_sizes, int n_in,
                              void* d_out, int out_size, void* d_ws, size_t ws_size,
                              hipStream_t stream) {
    const float* x    = (const float*)d_in[0];
    const int*   ei   = (const int*)d_in[1];
    const float* attr = (const float*)d_in[2];
    const int*   mt   = (const int*)d_in[3];
    const int*   mg   = (const int*)d_in[4];
    const int*   mp   = (const int*)d_in[5];
    const float* Wf   = (const float*)d_in[24];
    const float* bf   = (const float*)d_in[25];
    const float* W2   = (const float*)d_in[26];
    const float* a2s  = (const float*)d_in[27];
    const float* a2d  = (const float*)d_in[28];
    const float* b2   = (const float*)d_in[29];
    const float* W3   = (const float*)d_in[30];
    const float* a3s  = (const float*)d_in[31];
    const float* a3d  = (const float*)d_in[32];
    const float* b3   = (const float*)d_in[33];
    const float* Wc1  = (const float*)d_in[34];
    const float* bc1  = (const float*)d_in[35];
    const float* Wc2  = (const float*)d_in[36];
    const float* bc2  = (const float*)d_in[37];

    int N = in_sizes[0];
    int E = in_sizes[1] / 2;

    char* w = (char*)d_ws;
    auto alloc = [&](size_t bytes) {
        char* p = w;
        w += (bytes + 255) & ~(size_t)255;
        return p;
    };
    int* off      = (int*)alloc((size_t)(N + 1) * 4);
    int* cursor   = (int*)alloc((size_t)N * 4);
    int* deg      = (int*)alloc((size_t)N * 4);
    int* partials = (int*)alloc(1024 * 4);
    int* csr_src  = (int*)alloc((size_t)E * 4);
    ConstBuf* cb  = (ConstBuf*)alloc(sizeof(ConstBuf));
    float* as_    = (float*)alloc((size_t)N * 4 * 4);
    float* ad_    = (float*)alloc((size_t)N * 4 * 4);
    float* bufA   = (float*)alloc((size_t)N * 128 * 4);
    float4* rec   = (float4*)alloc((size_t)E * 16);
    unsigned short* hxb = (unsigned short*)alloc((size_t)N * 256);

    PreArgs pa;
    for (int b = 0; b < 3; ++b) {
        pa.br[b].W   = (const float*)d_in[6 + b * 6 + 0];
        pa.br[b].as_ = (const float*)d_in[6 + b * 6 + 1];
        pa.br[b].ad_ = (const float*)d_in[6 + b * 6 + 2];
        pa.br[b].ae  = (const float*)d_in[6 + b * 6 + 3];
        pa.br[b].We  = (const float*)d_in[6 + b * 6 + 4];
        pa.br[b].b   = (const float*)d_in[6 + b * 6 + 5];
    }
    pa.Wf = Wf; pa.bf = bf; pa.cb = cb;

    int total = N + 1;
    int nScanBlocks = (total + SCAN_EPB - 1) / SCAN_EPB;

    hipMemsetAsync(deg, 0, (size_t)N * 4, stream);
    hipLaunchKernelGGL(k_precompute, dim3(1), dim3(256), 0, stream, pa);
    int gE = (E + 255) / 256;
    hipLaunchKernelGGL(k_count, dim3(gE), dim3(256), 0, stream, ei, E, deg);
    hipLaunchKernelGGL(k_scan1, dim3(nScanBlocks), dim3(256), 0, stream, deg, off, partials, total);
    hipLaunchKernelGGL(k_scan2, dim3(1), dim3(256), 0, stream, partials, nScanBlocks);
    hipLaunchKernelGGL(k_scan3, dim3((total + 255) / 256), dim3(256), 0, stream,
                       off, partials, cursor, total);
    hipLaunchKernelGGL(k_scatter, dim3(gE), dim3(256), 0, stream,
                       ei, attr, mt, mg, mp, E, cursor, rec);
    hipLaunchKernelGGL(k_branch, dim3((N + 15) / 16), dim3(256), 0, stream,
                       x, off, rec, csr_src, cb, bufA, N);
    // conv2
    hipLaunchKernelGGL(k_mm128s, dim3((N + 7) / 8), dim3(128), 0, stream,
                       bufA, W2, a2s, a2d, hxb, as_, ad_, N);
    hipLaunchKernelGGL(k_gatagg, dim3((N + 3) / 4), dim3(256), 0, stream,
                       hxb, as_, ad_, b2, off, csr_src, bufA, N);
    // conv3
    hipLaunchKernelGGL(k_mm128s, dim3((N + 7) / 8), dim3(128), 0, stream,
                       bufA, W3, a3s, a3d, hxb, as_, ad_, N);
    hipLaunchKernelGGL(k_gatagg, dim3((N + 3) / 4), dim3(256), 0, stream,
                       hxb, as_, ad_, b3, off, csr_src, bufA, N);
    // classifier
    hipLaunchKernelGGL(k_cls, dim3((N + CLS_NPB - 1) / CLS_NPB), dim3(256), 0, stream,
                       bufA, Wc1, bc1, Wc2, bc2, (float*)d_out, N);
}